// Round 3
// baseline (493.349 us; speedup 1.0000x reference)
//
#include <hip/hip_runtime.h>

#define WF 257
#define LAM 0.01f
#define ROWL 578
#define LP16(i) ((i) + (((i)>>4)<<1))

typedef __attribute__((ext_vector_type(8))) short short8;
typedef __attribute__((ext_vector_type(4))) float f32x4;

__device__ __forceinline__ ushort f2bf(float f){
    unsigned u = __float_as_uint(f);
    unsigned r = (u + 0x7fffu + ((u >> 16) & 1u)) >> 16;
    return (ushort)r;
}

__device__ __forceinline__ int drev(int x){ return ((x&7)<<6) | (x&56) | ((x>>6)&7); }

__device__ __forceinline__ float2 cmul(float2 a, float2 b){
    return make_float2(a.x*b.x - a.y*b.y, a.x*b.y + a.y*b.x);
}
__device__ __forceinline__ float2 cadd(float2 a, float2 b){ return make_float2(a.x+b.x, a.y+b.y); }
__device__ __forceinline__ float2 csub(float2 a, float2 b){ return make_float2(a.x-b.x, a.y-b.y); }

template<bool INV>
__device__ __forceinline__ void dft8(float2 v[8]) {
    const float R = 0.70710678118654752f;
    float2 y0=v[0], y1=v[4], y2=v[2], y3=v[6], y4=v[1], y5=v[5], y6=v[3], y7=v[7];
    float2 t;
    t=y1; y1=csub(y0,t); y0=cadd(y0,t);
    t=y3; y3=csub(y2,t); y2=cadd(y2,t);
    t=y5; y5=csub(y4,t); y4=cadd(y4,t);
    t=y7; y7=csub(y6,t); y6=cadd(y6,t);
    t=y2; y2=csub(y0,t); y0=cadd(y0,t);
    t = INV ? make_float2(-y3.y, y3.x) : make_float2(y3.y, -y3.x);
    y3=csub(y1,t); y1=cadd(y1,t);
    t=y6; y6=csub(y4,t); y4=cadd(y4,t);
    t = INV ? make_float2(-y7.y, y7.x) : make_float2(y7.y, -y7.x);
    y7=csub(y5,t); y5=cadd(y5,t);
    t=y4; y4=csub(y0,t); y0=cadd(y0,t);
    { float2 w8 = INV ? make_float2(R, R) : make_float2(R,-R);
      t=cmul(y5,w8); y5=csub(y1,t); y1=cadd(y1,t); }
    t = INV ? make_float2(-y6.y, y6.x) : make_float2(y6.y, -y6.x);
    y6=csub(y2,t); y2=cadd(y2,t);
    { float2 w8 = INV ? make_float2(-R, R) : make_float2(-R,-R);
      t=cmul(y7,w8); y7=csub(y3,t); y3=cadd(y3,t); }
    v[0]=y0; v[1]=y1; v[2]=y2; v[3]=y3; v[4]=y4; v[5]=y5; v[6]=y6; v[7]=y7;
}

// 512-pt radix-8 FFT; digit-reversed input, natural output. twg in global (L1-hot).
template<int NROWS, int NTHREADS, bool INV>
__device__ __forceinline__ void fft512_r8(float2* d, const float2* __restrict__ twg, int tid)
{
    // stage 0: contiguous octets -> float4 LDS ops
    __syncthreads();
    #pragma unroll
    for (int rep = 0; rep < (NROWS*64)/NTHREADS; ++rep) {
        int slot = rep*NTHREADS + tid;
        int row = slot >> 6;
        int j = slot & 63;
        float4* p = (float4*)(d + row*ROWL + LP16(j*8));
        float2 v[8];
        float4 a0 = p[0], a1 = p[1], a2 = p[2], a3 = p[3];
        v[0]=make_float2(a0.x,a0.y); v[1]=make_float2(a0.z,a0.w);
        v[2]=make_float2(a1.x,a1.y); v[3]=make_float2(a1.z,a1.w);
        v[4]=make_float2(a2.x,a2.y); v[5]=make_float2(a2.z,a2.w);
        v[6]=make_float2(a3.x,a3.y); v[7]=make_float2(a3.z,a3.w);
        dft8<INV>(v);
        p[0]=make_float4(v[0].x,v[0].y,v[1].x,v[1].y);
        p[1]=make_float4(v[2].x,v[2].y,v[3].x,v[3].y);
        p[2]=make_float4(v[4].x,v[4].y,v[5].x,v[5].y);
        p[3]=make_float4(v[6].x,v[6].y,v[7].x,v[7].y);
    }
    #pragma unroll
    for (int s = 1; s < 3; ++s) {
        const int hlen = (s==1) ? 8 : 64;
        const int T    = (s==1) ? 8 : 1;
        __syncthreads();
        #pragma unroll
        for (int rep = 0; rep < (NROWS*64)/NTHREADS; ++rep) {
            int slot = rep*NTHREADS + tid;
            int row = slot >> 6;
            int j = slot & 63;
            int p = j & (hlen-1);
            int base = row*ROWL;
            int i0 = (j - p)*8 + p;
            float2 v[8];
            #pragma unroll
            for (int q = 0; q < 8; ++q) {
                float2 a = d[base + LP16(i0 + q*hlen)];
                if (q > 0) {
                    float2 wv = twg[(p*q*T) & 511];
                    if (INV) wv.y = -wv.y;
                    a = cmul(a, wv);
                }
                v[q] = a;
            }
            dft8<INV>(v);
            #pragma unroll
            for (int q = 0; q < 8; ++q)
                d[base + LP16(i0 + q*hlen)] = v[q];
        }
    }
    __syncthreads();
}

__global__ void k_twiddle(float2* __restrict__ twg){
    int t = blockIdx.x*256 + threadIdx.x;
    if (t < 512) {
        float s, c;
        sincosf((float)t * (-6.2831853071795864769f/512.0f), &s, &c);
        twg[t] = make_float2(c, s);
    }
}

// ---------------- weight prep: bf16 MFMA A-fragments ----------------
__global__ void k_wprep(const float* __restrict__ w, ushort* __restrict__ wtp){
    int i = blockIdx.x*256 + threadIdx.x;
    if (i < 9216) {
        int j = i & 7, l = (i>>3) & 63, m = (i>>9) & 1, tap = i >> 10;
        int co = m*16 + (l & 15), ci = ((l>>4)&3)*8 + j;
        wtp[i] = f2bf(w[(co*32 + ci)*9 + tap]);
    }
}

// ---------------- NCHW fp32 -> NHWC bf16 transpose ----------------
__global__ __launch_bounds__(256) void k_transpose(const float* __restrict__ x, ushort* __restrict__ xt){
    __shared__ ushort tl[64][36];
    const int tid = threadIdx.x;
    const int w0 = blockIdx.x*64, h = blockIdx.y, b = blockIdx.z;
    #pragma unroll
    for (int it = 0; it < 8; ++it) {
        int i = it*256 + tid, c = i >> 6, ww = i & 63;
        tl[ww][c] = f2bf(x[(((size_t)b*32 + c)*512 + h)*512 + w0 + ww]);
    }
    __syncthreads();
    const int ww = tid >> 2, c0 = (tid & 3) * 8;
    uint4 v;
    v.x = *(const uint*)&tl[ww][c0+0];
    v.y = *(const uint*)&tl[ww][c0+2];
    v.z = *(const uint*)&tl[ww][c0+4];
    v.w = *(const uint*)&tl[ww][c0+6];
    *(uint4*)(xt + ((((size_t)b*512 + h)*512 + w0 + ww)*32 + c0)) = v;
}

// ---------------- conv 3x3 via bf16 MFMA, fused bias + BN1 stats ----------------
__global__ __launch_bounds__(256) void k_conv_mfma(
    const ushort* __restrict__ xt, const ushort* __restrict__ wtp,
    const float* __restrict__ bias, float* __restrict__ out, float* __restrict__ stats)
{
    __shared__ float sred[64];
    const int tid = threadIdx.x;
    const int wid = tid >> 6, lane = tid & 63;
    const int h = blockIdx.y*4 + wid;
    const int w0 = blockIdx.x*64;
    const int b = blockIdx.z;

    short8 wa[9][2];
    #pragma unroll
    for (int tap = 0; tap < 9; ++tap)
        #pragma unroll
        for (int m = 0; m < 2; ++m)
            wa[tap][m] = *reinterpret_cast<const short8*>(wtp + ((tap*2 + m)*64 + lane)*8);

    f32x4 acc[2][4];
    #pragma unroll
    for (int m = 0; m < 2; ++m)
        #pragma unroll
        for (int n = 0; n < 4; ++n)
            acc[m][n] = (f32x4){0.f, 0.f, 0.f, 0.f};

    const int c0 = ((lane >> 4) & 3) * 8;
    const int pw = w0 + (lane & 15);
    const size_t ibase = (size_t)b * 512 * 512;

    #pragma unroll
    for (int dy = -1; dy <= 1; ++dy) {
        const int hh = h + dy;
        const bool hok = (unsigned)hh < 512u;
        #pragma unroll
        for (int dx = -1; dx <= 1; ++dx) {
            const int tap = (dy+1)*3 + (dx+1);
            short8 bfr[4];
            #pragma unroll
            for (int n = 0; n < 4; ++n) {
                const int ww = pw + n*16 + dx;
                short8 v = {0,0,0,0,0,0,0,0};
                if (hok && (unsigned)ww < 512u)
                    v = *reinterpret_cast<const short8*>(xt + ((ibase + (size_t)hh*512 + ww)*32 + c0));
                bfr[n] = v;
            }
            #pragma unroll
            for (int m = 0; m < 2; ++m)
                #pragma unroll
                for (int n = 0; n < 4; ++n)
                    acc[m][n] = __builtin_amdgcn_mfma_f32_16x16x32_bf16(wa[tap][m], bfr[n], acc[m][n], 0, 0, 0);
        }
    }

    if (tid < 64) sred[tid] = 0.f;
    __syncthreads();

    float bv[2][4];
    #pragma unroll
    for (int m = 0; m < 2; ++m)
        #pragma unroll
        for (int r = 0; r < 4; ++r)
            bv[m][r] = bias[m*16 + ((lane>>4)&3)*4 + r];

    float s8[8], q8[8];
    #pragma unroll
    for (int i = 0; i < 8; ++i) { s8[i] = 0.f; q8[i] = 0.f; }

    #pragma unroll
    for (int m = 0; m < 2; ++m) {
        #pragma unroll
        for (int n = 0; n < 4; ++n) {
            #pragma unroll
            for (int r = 0; r < 4; ++r) {
                const int co = m*16 + ((lane>>4)&3)*4 + r;
                const int ww = w0 + n*16 + (lane & 15);
                float val = acc[m][n][r] + bv[m][r];
                out[(((size_t)b*32 + co)*512 + h)*512 + ww] = val;
                s8[m*4+r] += val;
                q8[m*4+r] += val*val;
            }
        }
    }
    #pragma unroll
    for (int i = 0; i < 8; ++i) {
        #pragma unroll
        for (int off = 1; off < 16; off <<= 1) {
            s8[i] += __shfl_xor(s8[i], off, 64);
            q8[i] += __shfl_xor(q8[i], off, 64);
        }
    }
    if ((lane & 15) == 0) {
        #pragma unroll
        for (int m = 0; m < 2; ++m)
            #pragma unroll
            for (int r = 0; r < 4; ++r) {
                const int co = m*16 + ((lane>>4)&3)*4 + r;
                atomicAdd(&sred[co], s8[m*4+r]);
                atomicAdd(&sred[32+co], q8[m*4+r]);
            }
    }
    __syncthreads();
    if (tid < 64) {
        int bin = (blockIdx.y*8 + blockIdx.x + blockIdx.z) & 63;
        atomicAdd(&stats[bin*64 + tid], sred[tid]);
    }
}

__global__ void k_finalize(const float* __restrict__ stats, int nbins, const float* __restrict__ g,
                           const float* __restrict__ bta, float* __restrict__ bnp)
{
    int c = threadIdx.x;
    if (c < 32) {
        float s = 0.f, q = 0.f;
        for (int i = 0; i < nbins; ++i) { s += stats[i*64 + c]; q += stats[i*64 + 32 + c]; }
        const float inv_n = 1.f/1048576.f;
        float mean = s * inv_n;
        float var  = q * inv_n - mean*mean;
        float sc = g[c] * rsqrtf(var + 1e-5f);
        bnp[c] = sc;
        bnp[32+c] = bta[c] - mean*sc;
    }
}

// BN2 params from spectral (Parseval) sums + y-moments
__global__ void k_finalize2(const float* __restrict__ ystats, const float* __restrict__ sstats,
                            const float* __restrict__ g, const float* __restrict__ bta,
                            float* __restrict__ bnp2)
{
    int c = threadIdx.x;
    if (c < 32) {
        float Sy = 0.f, Sy2 = 0.f, Sgg = 0.f, Sgu = 0.f, Sg0 = 0.f;
        for (int i = 0; i < 64; ++i){ Sy  += ystats[i*64 + c]; Sy2 += ystats[i*64 + 32 + c]; }
        for (int i = 0; i < 32; ++i){ Sgg += sstats[i*96 + c]; Sgu += sstats[i*96 + 32 + c]; Sg0 += sstats[i*96 + 64 + c]; }
        const float inv_n = 1.f/1048576.f;
        float Sfo  = Sg0 + Sy;
        float Sfo2 = Sgg*(1.f/512.f) + Sgu*(2.f/512.f) + Sy2;
        float mean = Sfo*inv_n;
        float var  = Sfo2*inv_n - mean*mean;
        float sc = g[c]*rsqrtf(var + 1e-5f);
        bnp2[c] = sc;
        bnp2[32+c] = bta[c] - mean*sc;
    }
}

// ---------------- row rfft (W), fused BN1+ReLU + y-moments, transposed write ----------------
__global__ __launch_bounds__(512) void k_rowfft_fwd(
    const float* __restrict__ cvo, const float* __restrict__ bnp,
    const float2* __restrict__ twg, float2* __restrict__ spec, float* __restrict__ ystats)
{
    __shared__ float2 d[8*ROWL];
    __shared__ float red[16];
    const int tid = threadIdx.x;
    const int h0 = blockIdx.x * 8;
    const int bc = blockIdx.y;
    const int c = bc & 31;
    const float s1 = bnp[c], t1 = bnp[32+c];
    float ls = 0.f, lsq = 0.f;
    #pragma unroll
    for (int r = 0; r < 8; ++r) {
        float v = cvo[((size_t)bc*512 + h0 + r)*512 + tid];
        float y = fmaxf(fmaf(v, s1, t1), 0.f);
        ls += y; lsq += y*y;
        d[r*ROWL + LP16(drev(tid))] = make_float2(y, 0.f);
    }
    fft512_r8<8,512,false>(d, twg, tid);
    for (int i = tid; i < 8*WF; i += 512) {
        int ho = i & 7, w = i >> 3;
        spec[((size_t)bc*WF + w)*512 + h0 + ho] = d[ho*ROWL + LP16(w)];
    }
    #pragma unroll
    for (int off = 32; off; off >>= 1){ ls += __shfl_down(ls, off, 64); lsq += __shfl_down(lsq, off, 64); }
    if ((tid & 63) == 0){ red[(tid>>6)*2] = ls; red[(tid>>6)*2+1] = lsq; }
    __syncthreads();
    if (tid == 0) {
        float a = 0.f, b = 0.f;
        #pragma unroll
        for (int i = 0; i < 8; ++i){ a += red[i*2]; b += red[i*2+1]; }
        int bin = blockIdx.x & 63;
        atomicAdd(&ystats[bin*64 + c], a);
        atomicAdd(&ystats[bin*64 + 32 + c], b);
    }
}

// ---------------- col FFT + MLP/gate + inverse col FFT + spectral BN2 sums ----------------
__global__ __launch_bounds__(256) void k_colfft(float2* __restrict__ spec,
    const float* __restrict__ w1, const float* __restrict__ b1,
    const float* __restrict__ w2, const float* __restrict__ b2,
    const float2* __restrict__ twg, float* __restrict__ sstats)
{
    __shared__ float2 d[4*ROWL];
    __shared__ float wl[80];
    __shared__ float red[4][12];
    const int tid = threadIdx.x;
    const int w = blockIdx.x;
    const int k = blockIdx.y;
    const int b = blockIdx.z;
    if (tid < 16) {
        wl[tid]      = w1[k*16 + tid];
        wl[16 + tid] = w1[128 + k*16 + tid];
        wl[32 + tid] = w2[k*16 + tid];
        wl[48 + tid] = w2[128 + k*16 + tid];
    } else if (tid < 20) {
        int o = tid - 16;
        wl[64 + o] = b1[k*4 + o];
        wl[68 + o] = b1[32 + k*4 + o];
        wl[72 + o] = b2[k*4 + o];
        wl[76 + o] = b2[32 + k*4 + o];
    }
    const size_t base0 = ((size_t)(b*32 + k*4)*WF + w) * 512;
    float4 uv[4];
    #pragma unroll
    for (int cc = 0; cc < 4; ++cc) {
        float4 v = ((const float4*)(spec + base0 + (size_t)cc*(WF*512)))[tid];
        uv[cc] = v;
        d[cc*ROWL + LP16(drev(2*tid))]   = make_float2(v.x, v.y);
        d[cc*ROWL + LP16(drev(2*tid+1))] = make_float2(v.z, v.w);
    }
    fft512_r8<4,256,false>(d, twg, tid);
    float zr[2][4], zi[2][4];
    #pragma unroll
    for (int rep = 0; rep < 2; ++rep) {
        const int ph = LP16(rep*256 + tid);
        float xr[4], xi[4];
        #pragma unroll
        for (int i = 0; i < 4; ++i) {
            float2 v = d[i*ROWL + ph];
            xr[i] = v.x * (1.f/512.f);
            xi[i] = v.y * (1.f/512.f);
        }
        float o1r[4], o1i[4];
        #pragma unroll
        for (int o = 0; o < 4; ++o) {
            float sr = wl[64+o], si = wl[68+o];
            #pragma unroll
            for (int i = 0; i < 4; ++i) {
                float wr = wl[i*4+o], wi = wl[16 + i*4+o];
                sr += xr[i]*wr - xi[i]*wi;
                si += xi[i]*wr + xr[i]*wi;
            }
            o1r[o] = fmaxf(sr, 0.f);
            o1i[o] = fmaxf(si, 0.f);
        }
        #pragma unroll
        for (int o = 0; o < 4; ++o) {
            float sr = wl[72+o], si = wl[76+o];
            #pragma unroll
            for (int i = 0; i < 4; ++i) {
                float wr = wl[32 + i*4+o], wi = wl[48 + i*4+o];
                sr += o1r[i]*wr - o1i[i]*wi;
                si += o1i[i]*wr + o1r[i]*wi;
            }
            sr = (sr > LAM) ? sr - LAM : ((sr < -LAM) ? sr + LAM : 0.f);
            si = (si > LAM) ? si - LAM : ((si < -LAM) ? si + LAM : 0.f);
            zr[rep][o] = sr*xr[o] - si*xi[o];
            zi[rep][o] = sr*xi[o] + si*xr[o];
        }
    }
    __syncthreads();
    #pragma unroll
    for (int rep = 0; rep < 2; ++rep) {
        const int hb = LP16(drev(rep*256 + tid));
        #pragma unroll
        for (int cc = 0; cc < 4; ++cc)
            d[cc*ROWL + hb] = make_float2(zr[rep][cc], zi[rep][cc]);
    }
    fft512_r8<4,256,true>(d, twg, tid);
    const bool edge = (w == 0) || (w == 256);
    float fl[12];
    #pragma unroll
    for (int i = 0; i < 12; ++i) fl[i] = 0.f;
    #pragma unroll
    for (int cc = 0; cc < 4; ++cc) {
        float2 a  = d[cc*ROWL + LP16(2*tid)];
        float2 bb = d[cc*ROWL + LP16(2*tid+1)];
        ((float4*)(spec + base0 + (size_t)cc*(WF*512)))[tid] = make_float4(a.x, a.y, bb.x, bb.y);
        if (edge) {
            fl[cc]   += a.x*a.x + bb.x*bb.x;
            fl[4+cc] += a.x*uv[cc].x + bb.x*uv[cc].z;
            if (w == 0) fl[8+cc] += a.x + bb.x;
        } else {
            fl[cc]   += 2.f*(a.x*a.x + a.y*a.y + bb.x*bb.x + bb.y*bb.y);
            fl[4+cc] += 2.f*(a.x*uv[cc].x + a.y*uv[cc].y + bb.x*uv[cc].z + bb.y*uv[cc].w);
        }
    }
    #pragma unroll
    for (int i = 0; i < 12; ++i)
        #pragma unroll
        for (int off = 32; off; off >>= 1)
            fl[i] += __shfl_down(fl[i], off, 64);
    const int wid = tid >> 6, lane = tid & 63;
    if (lane == 0)
        #pragma unroll
        for (int i = 0; i < 12; ++i) red[wid][i] = fl[i];
    __syncthreads();
    if (tid < 12) {
        float v = red[0][tid] + red[1][tid] + red[2][tid] + red[3][tid];
        int type = tid >> 2, cc = tid & 3;
        if (type < 2 || w == 0) {
            int bin = (w + b*8 + k) & 31;
            atomicAdd(&sstats[bin*96 + type*32 + k*4 + cc], v);
        }
    }
}

// ---------------- row irfft (W) + residual + BN2 + final ReLU, single write ----------------
__global__ __launch_bounds__(512) void k_rowfft_inv(
    const float2* __restrict__ spec, const float* __restrict__ cvo,
    const float* __restrict__ bnp, const float* __restrict__ bnp2,
    const float2* __restrict__ twg, float* __restrict__ out)
{
    __shared__ float2 d[8*ROWL];
    const int tid = threadIdx.x;
    const int h0 = blockIdx.x * 8;
    const int bc = blockIdx.y;
    const int c = bc & 31;
    for (int i = tid; i < 8*WF; i += 512) {
        int ho = i & 7, w = i >> 3;
        float2 v = spec[((size_t)bc*WF + w)*512 + h0 + ho];
        d[ho*ROWL + LP16(drev(w))] = v;
        if ((unsigned)(w - 1) < 255u)
            d[ho*ROWL + LP16(drev(512 - w))] = make_float2(v.x, -v.y);
    }
    fft512_r8<8,512,true>(d, twg, tid);
    const float s1 = bnp[c],  t1 = bnp[32+c];
    const float s2 = bnp2[c], t2 = bnp2[32+c];
    #pragma unroll
    for (int r = 0; r < 8; ++r) {
        size_t gi = ((size_t)bc*512 + h0 + r)*512 + tid;
        float cv = cvo[gi];
        float yv = fmaxf(fmaf(cv, s1, t1), 0.f);
        float fo = fmaf(d[r*ROWL + LP16(tid)].x, (1.f/512.f), yv);
        out[gi] = fmaxf(yv + fmaf(fo, s2, t2), 0.f);
    }
}

extern "C" void kernel_launch(void* const* d_in, const int* in_sizes, int n_in,
                              void* d_out, int out_size, void* d_ws, size_t ws_size,
                              hipStream_t stream)
{
    const float* x      = (const float*)d_in[0];
    const float* conv_w = (const float*)d_in[1];
    const float* conv_b = (const float*)d_in[2];
    const float* bn1g   = (const float*)d_in[3];
    const float* bn1b   = (const float*)d_in[4];
    const float* w1     = (const float*)d_in[5];
    const float* b1     = (const float*)d_in[6];
    const float* w2     = (const float*)d_in[7];
    const float* b2     = (const float*)d_in[8];
    const float* bn2g   = (const float*)d_in[9];
    const float* bn2b   = (const float*)d_in[10];
    float* out = (float*)d_out;

    char* ws = (char*)d_ws;
    float2* spec  = (float2*)ws;                            // 134,742,016 B
    ushort* xt    = (ushort*)ws;                            // aliases spec (dead before spec written)
    float*  cvo   = (float*)(ws + 134742016);               // 134,217,728 B
    ushort* wtp   = (ushort*)(ws + 134742016 + 134217728);  // 18,432 B
    float*  stats = (float*)(ws + 134742016 + 134217728 + 18432);
    float* stats1 = stats;             // 4096 f (bn1 bins)
    float* ystats = stats + 4096;      // 4096 f
    float* sstats = stats + 8192;      // 3072 f
    float* bnp1   = stats + 11264;     // 64 f
    float* bnp2   = stats + 11328;     // 64 f
    float2* twg   = (float2*)(stats + 11392); // 512 float2

    hipMemsetAsync(stats, 0, 11264*sizeof(float), stream);
    k_twiddle<<<2, 256, 0, stream>>>(twg);
    k_wprep<<<36, 256, 0, stream>>>(conv_w, wtp);
    k_transpose<<<dim3(8,512,4), 256, 0, stream>>>(x, xt);
    k_conv_mfma<<<dim3(8,128,4), 256, 0, stream>>>(xt, wtp, conv_b, cvo, stats1);
    k_finalize<<<1, 64, 0, stream>>>(stats1, 64, bn1g, bn1b, bnp1);
    k_rowfft_fwd<<<dim3(64,128), 512, 0, stream>>>(cvo, bnp1, twg, spec, ystats);
    k_colfft<<<dim3(257,8,4), 256, 0, stream>>>(spec, w1, b1, w2, b2, twg, sstats);
    k_finalize2<<<1, 64, 0, stream>>>(ystats, sstats, bn2g, bn2b, bnp2);
    k_rowfft_inv<<<dim3(64,128), 512, 0, stream>>>(spec, cvo, bnp1, bnp2, twg, out);
}

// Round 4
// 441.711 us; speedup vs baseline: 1.1169x; 1.1169x over previous
//
#include <hip/hip_runtime.h>

#define WF 257
#define LAM 0.01f
#define ROWL 578
#define LP16(i) ((i) + (((i)>>4)<<1))

typedef __attribute__((ext_vector_type(8))) short short8;
typedef __attribute__((ext_vector_type(4))) float f32x4;

__device__ __forceinline__ ushort f2bf(float f){
    unsigned u = __float_as_uint(f);
    unsigned r = (u + 0x7fffu + ((u >> 16) & 1u)) >> 16;
    return (ushort)r;
}

__device__ __forceinline__ int drev(int x){ return ((x&7)<<6) | (x&56) | ((x>>6)&7); }

__device__ __forceinline__ float2 cmul(float2 a, float2 b){
    return make_float2(a.x*b.x - a.y*b.y, a.x*b.y + a.y*b.x);
}
__device__ __forceinline__ float2 cadd(float2 a, float2 b){ return make_float2(a.x+b.x, a.y+b.y); }
__device__ __forceinline__ float2 csub(float2 a, float2 b){ return make_float2(a.x-b.x, a.y-b.y); }

// copy global twiddle table into LDS (no sincosf, one vec load per thread)
template<int NTHREADS>
__device__ __forceinline__ void ld_tw(float2* tw, const float2* __restrict__ twg, int tid){
    #pragma unroll
    for (int i = 0; i < 512/NTHREADS; ++i) {
        int t = i*NTHREADS + tid;
        ((float4*)tw)[t] = ((const float4*)twg)[t];   // 2 twiddles per float4
    }
}

template<bool INV>
__device__ __forceinline__ void dft8(float2 v[8]) {
    const float R = 0.70710678118654752f;
    float2 y0=v[0], y1=v[4], y2=v[2], y3=v[6], y4=v[1], y5=v[5], y6=v[3], y7=v[7];
    float2 t;
    t=y1; y1=csub(y0,t); y0=cadd(y0,t);
    t=y3; y3=csub(y2,t); y2=cadd(y2,t);
    t=y5; y5=csub(y4,t); y4=cadd(y4,t);
    t=y7; y7=csub(y6,t); y6=cadd(y6,t);
    t=y2; y2=csub(y0,t); y0=cadd(y0,t);
    t = INV ? make_float2(-y3.y, y3.x) : make_float2(y3.y, -y3.x);
    y3=csub(y1,t); y1=cadd(y1,t);
    t=y6; y6=csub(y4,t); y4=cadd(y4,t);
    t = INV ? make_float2(-y7.y, y7.x) : make_float2(y7.y, -y7.x);
    y7=csub(y5,t); y5=cadd(y5,t);
    t=y4; y4=csub(y0,t); y0=cadd(y0,t);
    { float2 w8 = INV ? make_float2(R, R) : make_float2(R,-R);
      t=cmul(y5,w8); y5=csub(y1,t); y1=cadd(y1,t); }
    t = INV ? make_float2(-y6.y, y6.x) : make_float2(y6.y, -y6.x);
    y6=csub(y2,t); y2=cadd(y2,t);
    { float2 w8 = INV ? make_float2(-R, R) : make_float2(-R,-R);
      t=cmul(y7,w8); y7=csub(y3,t); y3=cadd(y3,t); }
    v[0]=y0; v[1]=y1; v[2]=y2; v[3]=y3; v[4]=y4; v[5]=y5; v[6]=y6; v[7]=y7;
}

// 512-pt radix-8 FFT; digit-reversed input, natural output. tw in LDS.
template<int NROWS, int NTHREADS, bool INV>
__device__ __forceinline__ void fft512_r8(float2* d, const float2* tw, int tid)
{
    // stage 0: contiguous octets -> float4 LDS ops
    __syncthreads();
    #pragma unroll
    for (int rep = 0; rep < (NROWS*64)/NTHREADS; ++rep) {
        int slot = rep*NTHREADS + tid;
        int row = slot >> 6;
        int j = slot & 63;
        float4* p = (float4*)(d + row*ROWL + LP16(j*8));
        float2 v[8];
        float4 a0 = p[0], a1 = p[1], a2 = p[2], a3 = p[3];
        v[0]=make_float2(a0.x,a0.y); v[1]=make_float2(a0.z,a0.w);
        v[2]=make_float2(a1.x,a1.y); v[3]=make_float2(a1.z,a1.w);
        v[4]=make_float2(a2.x,a2.y); v[5]=make_float2(a2.z,a2.w);
        v[6]=make_float2(a3.x,a3.y); v[7]=make_float2(a3.z,a3.w);
        dft8<INV>(v);
        p[0]=make_float4(v[0].x,v[0].y,v[1].x,v[1].y);
        p[1]=make_float4(v[2].x,v[2].y,v[3].x,v[3].y);
        p[2]=make_float4(v[4].x,v[4].y,v[5].x,v[5].y);
        p[3]=make_float4(v[6].x,v[6].y,v[7].x,v[7].y);
    }
    #pragma unroll
    for (int s = 1; s < 3; ++s) {
        const int hlen = (s==1) ? 8 : 64;
        const int T    = (s==1) ? 8 : 1;
        __syncthreads();
        #pragma unroll
        for (int rep = 0; rep < (NROWS*64)/NTHREADS; ++rep) {
            int slot = rep*NTHREADS + tid;
            int row = slot >> 6;
            int j = slot & 63;
            int p = j & (hlen-1);
            int base = row*ROWL;
            int i0 = (j - p)*8 + p;
            float2 v[8];
            #pragma unroll
            for (int q = 0; q < 8; ++q) {
                float2 a = d[base + LP16(i0 + q*hlen)];
                if (q > 0) {
                    float2 wv = tw[(p*q*T) & 511];
                    if (INV) wv.y = -wv.y;
                    a = cmul(a, wv);
                }
                v[q] = a;
            }
            dft8<INV>(v);
            #pragma unroll
            for (int q = 0; q < 8; ++q)
                d[base + LP16(i0 + q*hlen)] = v[q];
        }
    }
    __syncthreads();
}

__global__ void k_twiddle(float2* __restrict__ twg){
    int t = blockIdx.x*256 + threadIdx.x;
    if (t < 512) {
        float s, c;
        sincosf((float)t * (-6.2831853071795864769f/512.0f), &s, &c);
        twg[t] = make_float2(c, s);
    }
}

// ---------------- weight prep: bf16 MFMA A-fragments ----------------
__global__ void k_wprep(const float* __restrict__ w, ushort* __restrict__ wtp){
    int i = blockIdx.x*256 + threadIdx.x;
    if (i < 9216) {
        int j = i & 7, l = (i>>3) & 63, m = (i>>9) & 1, tap = i >> 10;
        int co = m*16 + (l & 15), ci = ((l>>4)&3)*8 + j;
        wtp[i] = f2bf(w[(co*32 + ci)*9 + tap]);
    }
}

// ---------------- NCHW fp32 -> NHWC bf16 transpose ----------------
__global__ __launch_bounds__(256) void k_transpose(const float* __restrict__ x, ushort* __restrict__ xt){
    __shared__ ushort tl[64][36];
    const int tid = threadIdx.x;
    const int w0 = blockIdx.x*64, h = blockIdx.y, b = blockIdx.z;
    #pragma unroll
    for (int it = 0; it < 8; ++it) {
        int i = it*256 + tid, c = i >> 6, ww = i & 63;
        tl[ww][c] = f2bf(x[(((size_t)b*32 + c)*512 + h)*512 + w0 + ww]);
    }
    __syncthreads();
    const int ww = tid >> 2, c0 = (tid & 3) * 8;
    uint4 v;
    v.x = *(const uint*)&tl[ww][c0+0];
    v.y = *(const uint*)&tl[ww][c0+2];
    v.z = *(const uint*)&tl[ww][c0+4];
    v.w = *(const uint*)&tl[ww][c0+6];
    *(uint4*)(xt + ((((size_t)b*512 + h)*512 + w0 + ww)*32 + c0)) = v;
}

// ---------------- conv 3x3 via bf16 MFMA, fused bias + BN1 stats ----------------
__global__ __launch_bounds__(256) void k_conv_mfma(
    const ushort* __restrict__ xt, const ushort* __restrict__ wtp,
    const float* __restrict__ bias, float* __restrict__ out, float* __restrict__ stats)
{
    __shared__ float sred[64];
    const int tid = threadIdx.x;
    const int wid = tid >> 6, lane = tid & 63;
    const int h = blockIdx.y*4 + wid;
    const int w0 = blockIdx.x*64;
    const int b = blockIdx.z;

    short8 wa[9][2];
    #pragma unroll
    for (int tap = 0; tap < 9; ++tap)
        #pragma unroll
        for (int m = 0; m < 2; ++m)
            wa[tap][m] = *reinterpret_cast<const short8*>(wtp + ((tap*2 + m)*64 + lane)*8);

    f32x4 acc[2][4];
    #pragma unroll
    for (int m = 0; m < 2; ++m)
        #pragma unroll
        for (int n = 0; n < 4; ++n)
            acc[m][n] = (f32x4){0.f, 0.f, 0.f, 0.f};

    const int c0 = ((lane >> 4) & 3) * 8;
    const int pw = w0 + (lane & 15);
    const size_t ibase = (size_t)b * 512 * 512;

    #pragma unroll
    for (int dy = -1; dy <= 1; ++dy) {
        const int hh = h + dy;
        const bool hok = (unsigned)hh < 512u;
        #pragma unroll
        for (int dx = -1; dx <= 1; ++dx) {
            const int tap = (dy+1)*3 + (dx+1);
            short8 bfr[4];
            #pragma unroll
            for (int n = 0; n < 4; ++n) {
                const int ww = pw + n*16 + dx;
                short8 v = {0,0,0,0,0,0,0,0};
                if (hok && (unsigned)ww < 512u)
                    v = *reinterpret_cast<const short8*>(xt + ((ibase + (size_t)hh*512 + ww)*32 + c0));
                bfr[n] = v;
            }
            #pragma unroll
            for (int m = 0; m < 2; ++m)
                #pragma unroll
                for (int n = 0; n < 4; ++n)
                    acc[m][n] = __builtin_amdgcn_mfma_f32_16x16x32_bf16(wa[tap][m], bfr[n], acc[m][n], 0, 0, 0);
        }
    }

    if (tid < 64) sred[tid] = 0.f;
    __syncthreads();

    float bv[2][4];
    #pragma unroll
    for (int m = 0; m < 2; ++m)
        #pragma unroll
        for (int r = 0; r < 4; ++r)
            bv[m][r] = bias[m*16 + ((lane>>4)&3)*4 + r];

    float s8[8], q8[8];
    #pragma unroll
    for (int i = 0; i < 8; ++i) { s8[i] = 0.f; q8[i] = 0.f; }

    #pragma unroll
    for (int m = 0; m < 2; ++m) {
        #pragma unroll
        for (int n = 0; n < 4; ++n) {
            #pragma unroll
            for (int r = 0; r < 4; ++r) {
                const int co = m*16 + ((lane>>4)&3)*4 + r;
                const int ww = w0 + n*16 + (lane & 15);
                float val = acc[m][n][r] + bv[m][r];
                out[(((size_t)b*32 + co)*512 + h)*512 + ww] = val;
                s8[m*4+r] += val;
                q8[m*4+r] += val*val;
            }
        }
    }
    #pragma unroll
    for (int i = 0; i < 8; ++i) {
        #pragma unroll
        for (int off = 1; off < 16; off <<= 1) {
            s8[i] += __shfl_xor(s8[i], off, 64);
            q8[i] += __shfl_xor(q8[i], off, 64);
        }
    }
    if ((lane & 15) == 0) {
        #pragma unroll
        for (int m = 0; m < 2; ++m)
            #pragma unroll
            for (int r = 0; r < 4; ++r) {
                const int co = m*16 + ((lane>>4)&3)*4 + r;
                atomicAdd(&sred[co], s8[m*4+r]);
                atomicAdd(&sred[32+co], q8[m*4+r]);
            }
    }
    __syncthreads();
    if (tid < 64) {
        int bin = (blockIdx.y*8 + blockIdx.x + blockIdx.z) & 63;
        atomicAdd(&stats[bin*64 + tid], sred[tid]);
    }
}

__global__ void k_finalize(const float* __restrict__ stats, int nbins, const float* __restrict__ g,
                           const float* __restrict__ bta, float* __restrict__ bnp)
{
    int c = threadIdx.x;
    if (c < 32) {
        float s = 0.f, q = 0.f;
        for (int i = 0; i < nbins; ++i) { s += stats[i*64 + c]; q += stats[i*64 + 32 + c]; }
        const float inv_n = 1.f/1048576.f;
        float mean = s * inv_n;
        float var  = q * inv_n - mean*mean;
        float sc = g[c] * rsqrtf(var + 1e-5f);
        bnp[c] = sc;
        bnp[32+c] = bta[c] - mean*sc;
    }
}

// BN2 params from spectral (Parseval) sums + y-moments
__global__ void k_finalize2(const float* __restrict__ ystats, const float* __restrict__ sstats,
                            const float* __restrict__ g, const float* __restrict__ bta,
                            float* __restrict__ bnp2)
{
    int c = threadIdx.x;
    if (c < 32) {
        float Sy = 0.f, Sy2 = 0.f, Sgg = 0.f, Sgu = 0.f, Sg0 = 0.f;
        for (int i = 0; i < 64; ++i){ Sy  += ystats[i*64 + c]; Sy2 += ystats[i*64 + 32 + c]; }
        for (int i = 0; i < 32; ++i){ Sgg += sstats[i*96 + c]; Sgu += sstats[i*96 + 32 + c]; Sg0 += sstats[i*96 + 64 + c]; }
        const float inv_n = 1.f/1048576.f;
        float Sfo  = Sg0 + Sy;
        float Sfo2 = Sgg*(1.f/512.f) + Sgu*(2.f/512.f) + Sy2;
        float mean = Sfo*inv_n;
        float var  = Sfo2*inv_n - mean*mean;
        float sc = g[c]*rsqrtf(var + 1e-5f);
        bnp2[c] = sc;
        bnp2[32+c] = bta[c] - mean*sc;
    }
}

// ---------------- row rfft (W), fused BN1+ReLU + y-moments, transposed write ----------------
__global__ __launch_bounds__(512) void k_rowfft_fwd(
    const float* __restrict__ cvo, const float* __restrict__ bnp,
    const float2* __restrict__ twg, float2* __restrict__ spec, float* __restrict__ ystats)
{
    __shared__ float2 tw[512];
    __shared__ float2 d[8*ROWL];
    __shared__ float red[16];
    const int tid = threadIdx.x;
    const int h0 = blockIdx.x * 8;
    const int bc = blockIdx.y;
    const int c = bc & 31;
    ld_tw<512>(tw, twg, tid);
    const float s1 = bnp[c], t1 = bnp[32+c];
    float ls = 0.f, lsq = 0.f;
    #pragma unroll
    for (int r = 0; r < 8; ++r) {
        float v = cvo[((size_t)bc*512 + h0 + r)*512 + tid];
        float y = fmaxf(fmaf(v, s1, t1), 0.f);
        ls += y; lsq += y*y;
        d[r*ROWL + LP16(drev(tid))] = make_float2(y, 0.f);
    }
    fft512_r8<8,512,false>(d, tw, tid);
    for (int i = tid; i < 8*WF; i += 512) {
        int ho = i & 7, w = i >> 3;
        spec[((size_t)bc*WF + w)*512 + h0 + ho] = d[ho*ROWL + LP16(w)];
    }
    #pragma unroll
    for (int off = 32; off; off >>= 1){ ls += __shfl_down(ls, off, 64); lsq += __shfl_down(lsq, off, 64); }
    if ((tid & 63) == 0){ red[(tid>>6)*2] = ls; red[(tid>>6)*2+1] = lsq; }
    __syncthreads();
    if (tid == 0) {
        float a = 0.f, b = 0.f;
        #pragma unroll
        for (int i = 0; i < 8; ++i){ a += red[i*2]; b += red[i*2+1]; }
        int bin = blockIdx.x & 63;
        atomicAdd(&ystats[bin*64 + c], a);
        atomicAdd(&ystats[bin*64 + 32 + c], b);
    }
}

// ---------------- col FFT + MLP/gate + inverse col FFT + spectral BN2 sums ----------------
__global__ __launch_bounds__(256) void k_colfft(float2* __restrict__ spec,
    const float* __restrict__ w1, const float* __restrict__ b1,
    const float* __restrict__ w2, const float* __restrict__ b2,
    const float2* __restrict__ twg, float* __restrict__ sstats)
{
    __shared__ float2 tw[512];
    __shared__ float2 d[4*ROWL];
    __shared__ float wl[80];
    __shared__ float red[4][12];
    const int tid = threadIdx.x;
    const int w = blockIdx.x;
    const int k = blockIdx.y;
    const int b = blockIdx.z;
    ld_tw<256>(tw, twg, tid);
    if (tid < 16) {
        wl[tid]      = w1[k*16 + tid];
        wl[16 + tid] = w1[128 + k*16 + tid];
        wl[32 + tid] = w2[k*16 + tid];
        wl[48 + tid] = w2[128 + k*16 + tid];
    } else if (tid < 20) {
        int o = tid - 16;
        wl[64 + o] = b1[k*4 + o];
        wl[68 + o] = b1[32 + k*4 + o];
        wl[72 + o] = b2[k*4 + o];
        wl[76 + o] = b2[32 + k*4 + o];
    }
    const size_t base0 = ((size_t)(b*32 + k*4)*WF + w) * 512;
    float4 uv[4];
    #pragma unroll
    for (int cc = 0; cc < 4; ++cc) {
        float4 v = ((const float4*)(spec + base0 + (size_t)cc*(WF*512)))[tid];
        uv[cc] = v;
        d[cc*ROWL + LP16(drev(2*tid))]   = make_float2(v.x, v.y);
        d[cc*ROWL + LP16(drev(2*tid+1))] = make_float2(v.z, v.w);
    }
    fft512_r8<4,256,false>(d, tw, tid);
    float zr[2][4], zi[2][4];
    #pragma unroll
    for (int rep = 0; rep < 2; ++rep) {
        const int ph = LP16(rep*256 + tid);
        float xr[4], xi[4];
        #pragma unroll
        for (int i = 0; i < 4; ++i) {
            float2 v = d[i*ROWL + ph];
            xr[i] = v.x * (1.f/512.f);
            xi[i] = v.y * (1.f/512.f);
        }
        float o1r[4], o1i[4];
        #pragma unroll
        for (int o = 0; o < 4; ++o) {
            float sr = wl[64+o], si = wl[68+o];
            #pragma unroll
            for (int i = 0; i < 4; ++i) {
                float wr = wl[i*4+o], wi = wl[16 + i*4+o];
                sr += xr[i]*wr - xi[i]*wi;
                si += xi[i]*wr + xr[i]*wi;
            }
            o1r[o] = fmaxf(sr, 0.f);
            o1i[o] = fmaxf(si, 0.f);
        }
        #pragma unroll
        for (int o = 0; o < 4; ++o) {
            float sr = wl[72+o], si = wl[76+o];
            #pragma unroll
            for (int i = 0; i < 4; ++i) {
                float wr = wl[32 + i*4+o], wi = wl[48 + i*4+o];
                sr += o1r[i]*wr - o1i[i]*wi;
                si += o1i[i]*wr + o1r[i]*wi;
            }
            sr = (sr > LAM) ? sr - LAM : ((sr < -LAM) ? sr + LAM : 0.f);
            si = (si > LAM) ? si - LAM : ((si < -LAM) ? si + LAM : 0.f);
            zr[rep][o] = sr*xr[o] - si*xi[o];
            zi[rep][o] = sr*xi[o] + si*xr[o];
        }
    }
    __syncthreads();
    #pragma unroll
    for (int rep = 0; rep < 2; ++rep) {
        const int hb = LP16(drev(rep*256 + tid));
        #pragma unroll
        for (int cc = 0; cc < 4; ++cc)
            d[cc*ROWL + hb] = make_float2(zr[rep][cc], zi[rep][cc]);
    }
    fft512_r8<4,256,true>(d, tw, tid);
    const bool edge = (w == 0) || (w == 256);
    float fl[12];
    #pragma unroll
    for (int i = 0; i < 12; ++i) fl[i] = 0.f;
    #pragma unroll
    for (int cc = 0; cc < 4; ++cc) {
        float2 a  = d[cc*ROWL + LP16(2*tid)];
        float2 bb = d[cc*ROWL + LP16(2*tid+1)];
        ((float4*)(spec + base0 + (size_t)cc*(WF*512)))[tid] = make_float4(a.x, a.y, bb.x, bb.y);
        if (edge) {
            fl[cc]   += a.x*a.x + bb.x*bb.x;
            fl[4+cc] += a.x*uv[cc].x + bb.x*uv[cc].z;
            if (w == 0) fl[8+cc] += a.x + bb.x;
        } else {
            fl[cc]   += 2.f*(a.x*a.x + a.y*a.y + bb.x*bb.x + bb.y*bb.y);
            fl[4+cc] += 2.f*(a.x*uv[cc].x + a.y*uv[cc].y + bb.x*uv[cc].z + bb.y*uv[cc].w);
        }
    }
    #pragma unroll
    for (int i = 0; i < 12; ++i)
        #pragma unroll
        for (int off = 32; off; off >>= 1)
            fl[i] += __shfl_down(fl[i], off, 64);
    const int wid = tid >> 6, lane = tid & 63;
    if (lane == 0)
        #pragma unroll
        for (int i = 0; i < 12; ++i) red[wid][i] = fl[i];
    __syncthreads();
    if (tid < 12) {
        float v = red[0][tid] + red[1][tid] + red[2][tid] + red[3][tid];
        int type = tid >> 2, cc = tid & 3;
        if (type < 2 || w == 0) {
            int bin = (w + b*8 + k) & 31;
            atomicAdd(&sstats[bin*96 + type*32 + k*4 + cc], v);
        }
    }
}

// ---------------- row irfft (W) + residual + BN2 + final ReLU, single write ----------------
__global__ __launch_bounds__(512) void k_rowfft_inv(
    const float2* __restrict__ spec, const float* __restrict__ cvo,
    const float* __restrict__ bnp, const float* __restrict__ bnp2,
    const float2* __restrict__ twg, float* __restrict__ out)
{
    __shared__ float2 tw[512];
    __shared__ float2 d[8*ROWL];
    const int tid = threadIdx.x;
    const int h0 = blockIdx.x * 8;
    const int bc = blockIdx.y;
    const int c = bc & 31;
    ld_tw<512>(tw, twg, tid);
    for (int i = tid; i < 8*WF; i += 512) {
        int ho = i & 7, w = i >> 3;
        float2 v = spec[((size_t)bc*WF + w)*512 + h0 + ho];
        d[ho*ROWL + LP16(drev(w))] = v;
        if ((unsigned)(w - 1) < 255u)
            d[ho*ROWL + LP16(drev(512 - w))] = make_float2(v.x, -v.y);
    }
    fft512_r8<8,512,true>(d, tw, tid);
    const float s1 = bnp[c],  t1 = bnp[32+c];
    const float s2 = bnp2[c], t2 = bnp2[32+c];
    #pragma unroll
    for (int r = 0; r < 8; ++r) {
        size_t gi = ((size_t)bc*512 + h0 + r)*512 + tid;
        float cv = cvo[gi];
        float yv = fmaxf(fmaf(cv, s1, t1), 0.f);
        float fo = fmaf(d[r*ROWL + LP16(tid)].x, (1.f/512.f), yv);
        out[gi] = fmaxf(yv + fmaf(fo, s2, t2), 0.f);
    }
}

extern "C" void kernel_launch(void* const* d_in, const int* in_sizes, int n_in,
                              void* d_out, int out_size, void* d_ws, size_t ws_size,
                              hipStream_t stream)
{
    const float* x      = (const float*)d_in[0];
    const float* conv_w = (const float*)d_in[1];
    const float* conv_b = (const float*)d_in[2];
    const float* bn1g   = (const float*)d_in[3];
    const float* bn1b   = (const float*)d_in[4];
    const float* w1     = (const float*)d_in[5];
    const float* b1     = (const float*)d_in[6];
    const float* w2     = (const float*)d_in[7];
    const float* b2     = (const float*)d_in[8];
    const float* bn2g   = (const float*)d_in[9];
    const float* bn2b   = (const float*)d_in[10];
    float* out = (float*)d_out;

    char* ws = (char*)d_ws;
    float2* spec  = (float2*)ws;                            // 134,742,016 B
    ushort* xt    = (ushort*)ws;                            // aliases spec (dead before spec written)
    float*  cvo   = (float*)(ws + 134742016);               // 134,217,728 B
    ushort* wtp   = (ushort*)(ws + 134742016 + 134217728);  // 18,432 B
    float*  stats = (float*)(ws + 134742016 + 134217728 + 18432);
    float* stats1 = stats;             // 4096 f (bn1 bins)
    float* ystats = stats + 4096;      // 4096 f
    float* sstats = stats + 8192;      // 3072 f
    float* bnp1   = stats + 11264;     // 64 f
    float* bnp2   = stats + 11328;     // 64 f
    float2* twg   = (float2*)(stats + 11392); // 512 float2

    hipMemsetAsync(stats, 0, 11264*sizeof(float), stream);
    k_twiddle<<<2, 256, 0, stream>>>(twg);
    k_wprep<<<36, 256, 0, stream>>>(conv_w, wtp);
    k_transpose<<<dim3(8,512,4), 256, 0, stream>>>(x, xt);
    k_conv_mfma<<<dim3(8,128,4), 256, 0, stream>>>(xt, wtp, conv_b, cvo, stats1);
    k_finalize<<<1, 64, 0, stream>>>(stats1, 64, bn1g, bn1b, bnp1);
    k_rowfft_fwd<<<dim3(64,128), 512, 0, stream>>>(cvo, bnp1, twg, spec, ystats);
    k_colfft<<<dim3(257,8,4), 256, 0, stream>>>(spec, w1, b1, w2, b2, twg, sstats);
    k_finalize2<<<1, 64, 0, stream>>>(ystats, sstats, bn2g, bn2b, bnp2);
    k_rowfft_inv<<<dim3(64,128), 512, 0, stream>>>(spec, cvo, bnp1, bnp2, twg, out);
}

// Round 5
// 433.668 us; speedup vs baseline: 1.1376x; 1.0185x over previous
//
#include <hip/hip_runtime.h>

#define WF 257
#define LAM 0.01f
#define ROWL 588
#define LP(i) ((i) + (((i)>>4)<<1) + (((i)>>6)<<1))

typedef __attribute__((ext_vector_type(8))) short short8;
typedef __attribute__((ext_vector_type(4))) float f32x4;

__device__ __forceinline__ ushort f2bf(float f){
    unsigned u = __float_as_uint(f);
    unsigned r = (u + 0x7fffu + ((u >> 16) & 1u)) >> 16;
    return (ushort)r;
}

__device__ __forceinline__ float2 cmul(float2 a, float2 b){
    return make_float2(a.x*b.x - a.y*b.y, a.x*b.y + a.y*b.x);
}
__device__ __forceinline__ float2 cadd(float2 a, float2 b){ return make_float2(a.x+b.x, a.y+b.y); }
__device__ __forceinline__ float2 csub(float2 a, float2 b){ return make_float2(a.x-b.x, a.y-b.y); }

template<int NTHREADS>
__device__ __forceinline__ void ld_tw(float2* tw, const float2* __restrict__ twg, int tid){
    for (int t = tid; t < 256; t += NTHREADS)
        ((float4*)tw)[t] = ((const float4*)twg)[t];
}

template<bool INV>
__device__ __forceinline__ float2 twz(const float2* tw, int idx){
    float2 w = tw[idx];
    if (INV) w.y = -w.y;
    return w;
}

template<bool INV>
__device__ __forceinline__ void dft8(float2 v[8]) {
    const float R = 0.70710678118654752f;
    float2 y0=v[0], y1=v[4], y2=v[2], y3=v[6], y4=v[1], y5=v[5], y6=v[3], y7=v[7];
    float2 t;
    t=y1; y1=csub(y0,t); y0=cadd(y0,t);
    t=y3; y3=csub(y2,t); y2=cadd(y2,t);
    t=y5; y5=csub(y4,t); y4=cadd(y4,t);
    t=y7; y7=csub(y6,t); y6=cadd(y6,t);
    t=y2; y2=csub(y0,t); y0=cadd(y0,t);
    t = INV ? make_float2(-y3.y, y3.x) : make_float2(y3.y, -y3.x);
    y3=csub(y1,t); y1=cadd(y1,t);
    t=y6; y6=csub(y4,t); y4=cadd(y4,t);
    t = INV ? make_float2(-y7.y, y7.x) : make_float2(y7.y, -y7.x);
    y7=csub(y5,t); y5=cadd(y5,t);
    t=y4; y4=csub(y0,t); y0=cadd(y0,t);
    { float2 w8 = INV ? make_float2(R, R) : make_float2(R,-R);
      t=cmul(y5,w8); y5=csub(y1,t); y1=cadd(y1,t); }
    t = INV ? make_float2(-y6.y, y6.x) : make_float2(y6.y, -y6.x);
    y6=csub(y2,t); y2=cadd(y2,t);
    { float2 w8 = INV ? make_float2(-R, R) : make_float2(-R,-R);
      t=cmul(y7,w8); y7=csub(y3,t); y3=cadd(y3,t); }
    v[0]=y0; v[1]=y1; v[2]=y2; v[3]=y3; v[4]=y4; v[5]=y5; v[6]=y6; v[7]=y7;
}

// write stage-0 octet l contiguously (b128 x4, linear -> conflict-free)
__device__ __forceinline__ void oct_write(float2* drow, int l, const float2 v[8]){
    float4* p = (float4*)(drow + LP(8*l));
    p[0]=make_float4(v[0].x,v[0].y,v[1].x,v[1].y);
    p[1]=make_float4(v[2].x,v[2].y,v[3].x,v[3].y);
    p[2]=make_float4(v[4].x,v[4].y,v[5].x,v[5].y);
    p[3]=make_float4(v[6].x,v[6].y,v[7].x,v[7].y);
}

// gather stage-0 octet from natural-order LDS row: natural idx o0 + 64q
__device__ __forceinline__ void oct_gather(const float2* drow, int o0, float2 v[8]){
    const float2* b = drow + LP(o0);        // LP(o0+64q) == LP(o0) + 74q
    #pragma unroll
    for (int q = 0; q < 8; ++q) v[q] = b[74*q];
}

// stages 1+2 (in-place, with surrounding syncs). Stage-0 octets already in LDS.
template<int NROWS, int NTHREADS, bool INV>
__device__ __forceinline__ void fft_st12(float2* d, const float2* tw, int tid)
{
    __syncthreads();
    #pragma unroll
    for (int rep = 0; rep < (NROWS*64)/NTHREADS; ++rep){
        int slot = rep*NTHREADS + tid;
        int row = slot>>6, l = slot&63;
        int a = l&7, m = l>>3;
        float2* b = d + row*ROWL + 74*m + a;
        float2 v[8];
        v[0] = b[0];
        v[1] = cmul(b[8],  twz<INV>(tw, 8*a));
        v[2] = cmul(b[18], twz<INV>(tw, 16*a));
        v[3] = cmul(b[26], twz<INV>(tw, 24*a));
        v[4] = cmul(b[36], twz<INV>(tw, 32*a));
        v[5] = cmul(b[44], twz<INV>(tw, 40*a));
        v[6] = cmul(b[54], twz<INV>(tw, 48*a));
        v[7] = cmul(b[62], twz<INV>(tw, 56*a));
        dft8<INV>(v);
        b[0]=v[0]; b[8]=v[1]; b[18]=v[2]; b[26]=v[3]; b[36]=v[4]; b[44]=v[5]; b[54]=v[6]; b[62]=v[7];
    }
    __syncthreads();
    #pragma unroll
    for (int rep = 0; rep < (NROWS*64)/NTHREADS; ++rep){
        int slot = rep*NTHREADS + tid;
        int row = slot>>6, l = slot&63;
        float2* b = d + row*ROWL + l + 2*(l>>4);
        float2 v[8];
        v[0] = b[0];
        #pragma unroll
        for (int q = 1; q < 8; ++q)
            v[q] = cmul(b[74*q], twz<INV>(tw, (l*q)&511));
        dft8<INV>(v);
        #pragma unroll
        for (int q = 0; q < 8; ++q) b[74*q] = v[q];
    }
    __syncthreads();
}

__global__ void k_twiddle(float2* __restrict__ twg){
    int t = blockIdx.x*256 + threadIdx.x;
    if (t < 512) {
        float s, c;
        sincosf((float)t * (-6.2831853071795864769f/512.0f), &s, &c);
        twg[t] = make_float2(c, s);
    }
}

// ---------------- weight prep: bf16 MFMA A-fragments ----------------
__global__ void k_wprep(const float* __restrict__ w, ushort* __restrict__ wtp){
    int i = blockIdx.x*256 + threadIdx.x;
    if (i < 9216) {
        int j = i & 7, l = (i>>3) & 63, m = (i>>9) & 1, tap = i >> 10;
        int co = m*16 + (l & 15), ci = ((l>>4)&3)*8 + j;
        wtp[i] = f2bf(w[(co*32 + ci)*9 + tap]);
    }
}

// ---------------- NCHW fp32 -> NHWC bf16 transpose ----------------
__global__ __launch_bounds__(256) void k_transpose(const float* __restrict__ x, ushort* __restrict__ xt){
    __shared__ ushort tl[64][36];
    const int tid = threadIdx.x;
    const int w0 = blockIdx.x*64, h = blockIdx.y, b = blockIdx.z;
    #pragma unroll
    for (int it = 0; it < 8; ++it) {
        int i = it*256 + tid, c = i >> 6, ww = i & 63;
        tl[ww][c] = f2bf(x[(((size_t)b*32 + c)*512 + h)*512 + w0 + ww]);
    }
    __syncthreads();
    const int ww = tid >> 2, c0 = (tid & 3) * 8;
    uint4 v;
    v.x = *(const uint*)&tl[ww][c0+0];
    v.y = *(const uint*)&tl[ww][c0+2];
    v.z = *(const uint*)&tl[ww][c0+4];
    v.w = *(const uint*)&tl[ww][c0+6];
    *(uint4*)(xt + ((((size_t)b*512 + h)*512 + w0 + ww)*32 + c0)) = v;
}

// ---------------- conv 3x3 via bf16 MFMA, fused bias + BN1 stats ----------------
__global__ __launch_bounds__(256) void k_conv_mfma(
    const ushort* __restrict__ xt, const ushort* __restrict__ wtp,
    const float* __restrict__ bias, float* __restrict__ out, float* __restrict__ stats)
{
    __shared__ float sred[64];
    const int tid = threadIdx.x;
    const int wid = tid >> 6, lane = tid & 63;
    const int h = blockIdx.y*4 + wid;
    const int w0 = blockIdx.x*64;
    const int b = blockIdx.z;

    short8 wa[9][2];
    #pragma unroll
    for (int tap = 0; tap < 9; ++tap)
        #pragma unroll
        for (int m = 0; m < 2; ++m)
            wa[tap][m] = *reinterpret_cast<const short8*>(wtp + ((tap*2 + m)*64 + lane)*8);

    f32x4 acc[2][4];
    #pragma unroll
    for (int m = 0; m < 2; ++m)
        #pragma unroll
        for (int n = 0; n < 4; ++n)
            acc[m][n] = (f32x4){0.f, 0.f, 0.f, 0.f};

    const int c0 = ((lane >> 4) & 3) * 8;
    const int pw = w0 + (lane & 15);
    const size_t ibase = (size_t)b * 512 * 512;

    #pragma unroll
    for (int dy = -1; dy <= 1; ++dy) {
        const int hh = h + dy;
        const bool hok = (unsigned)hh < 512u;
        #pragma unroll
        for (int dx = -1; dx <= 1; ++dx) {
            const int tap = (dy+1)*3 + (dx+1);
            short8 bfr[4];
            #pragma unroll
            for (int n = 0; n < 4; ++n) {
                const int ww = pw + n*16 + dx;
                short8 v = {0,0,0,0,0,0,0,0};
                if (hok && (unsigned)ww < 512u)
                    v = *reinterpret_cast<const short8*>(xt + ((ibase + (size_t)hh*512 + ww)*32 + c0));
                bfr[n] = v;
            }
            #pragma unroll
            for (int m = 0; m < 2; ++m)
                #pragma unroll
                for (int n = 0; n < 4; ++n)
                    acc[m][n] = __builtin_amdgcn_mfma_f32_16x16x32_bf16(wa[tap][m], bfr[n], acc[m][n], 0, 0, 0);
        }
    }

    if (tid < 64) sred[tid] = 0.f;
    __syncthreads();

    float bv[2][4];
    #pragma unroll
    for (int m = 0; m < 2; ++m)
        #pragma unroll
        for (int r = 0; r < 4; ++r)
            bv[m][r] = bias[m*16 + ((lane>>4)&3)*4 + r];

    float s8[8], q8[8];
    #pragma unroll
    for (int i = 0; i < 8; ++i) { s8[i] = 0.f; q8[i] = 0.f; }

    #pragma unroll
    for (int m = 0; m < 2; ++m) {
        #pragma unroll
        for (int n = 0; n < 4; ++n) {
            #pragma unroll
            for (int r = 0; r < 4; ++r) {
                const int co = m*16 + ((lane>>4)&3)*4 + r;
                const int ww = w0 + n*16 + (lane & 15);
                float val = acc[m][n][r] + bv[m][r];
                out[(((size_t)b*32 + co)*512 + h)*512 + ww] = val;
                s8[m*4+r] += val;
                q8[m*4+r] += val*val;
            }
        }
    }
    #pragma unroll
    for (int i = 0; i < 8; ++i) {
        #pragma unroll
        for (int off = 1; off < 16; off <<= 1) {
            s8[i] += __shfl_xor(s8[i], off, 64);
            q8[i] += __shfl_xor(q8[i], off, 64);
        }
    }
    if ((lane & 15) == 0) {
        #pragma unroll
        for (int m = 0; m < 2; ++m)
            #pragma unroll
            for (int r = 0; r < 4; ++r) {
                const int co = m*16 + ((lane>>4)&3)*4 + r;
                atomicAdd(&sred[co], s8[m*4+r]);
                atomicAdd(&sred[32+co], q8[m*4+r]);
            }
    }
    __syncthreads();
    if (tid < 64) {
        int bin = (blockIdx.y*8 + blockIdx.x + blockIdx.z) & 63;
        atomicAdd(&stats[bin*64 + tid], sred[tid]);
    }
}

__global__ void k_finalize(const float* __restrict__ stats, int nbins, const float* __restrict__ g,
                           const float* __restrict__ bta, float* __restrict__ bnp)
{
    int c = threadIdx.x;
    if (c < 32) {
        float s = 0.f, q = 0.f;
        for (int i = 0; i < nbins; ++i) { s += stats[i*64 + c]; q += stats[i*64 + 32 + c]; }
        const float inv_n = 1.f/1048576.f;
        float mean = s * inv_n;
        float var  = q * inv_n - mean*mean;
        float sc = g[c] * rsqrtf(var + 1e-5f);
        bnp[c] = sc;
        bnp[32+c] = bta[c] - mean*sc;
    }
}

// BN2 params from spectral (Parseval) sums + y-moments
__global__ void k_finalize2(const float* __restrict__ ystats, const float* __restrict__ sstats,
                            const float* __restrict__ g, const float* __restrict__ bta,
                            float* __restrict__ bnp2)
{
    int c = threadIdx.x;
    if (c < 32) {
        float Sy = 0.f, Sy2 = 0.f, Sgg = 0.f, Sgu = 0.f, Sg0 = 0.f;
        for (int i = 0; i < 64; ++i){ Sy  += ystats[i*64 + c]; Sy2 += ystats[i*64 + 32 + c]; }
        for (int i = 0; i < 32; ++i){ Sgg += sstats[i*96 + c]; Sgu += sstats[i*96 + 32 + c]; Sg0 += sstats[i*96 + 64 + c]; }
        const float inv_n = 1.f/1048576.f;
        float Sfo  = Sg0 + Sy;
        float Sfo2 = Sgg*(1.f/512.f) + Sgu*(2.f/512.f) + Sy2;
        float mean = Sfo*inv_n;
        float var  = Sfo2*inv_n - mean*mean;
        float sc = g[c]*rsqrtf(var + 1e-5f);
        bnp2[c] = sc;
        bnp2[32+c] = bta[c] - mean*sc;
    }
}

// ---------------- row rfft (W): stage0 from global regs, BN1+ReLU + y-moments ----------------
__global__ __launch_bounds__(512) void k_rowfft_fwd(
    const float* __restrict__ cvo, const float* __restrict__ bnp,
    const float2* __restrict__ twg, float2* __restrict__ spec, float* __restrict__ ystats)
{
    __shared__ float2 tw[512];
    __shared__ float2 d[8*ROWL];
    __shared__ float red[16];
    const int tid = threadIdx.x;
    const int h0 = blockIdx.x * 8;
    const int bc = blockIdx.y;
    const int c = bc & 31;
    ld_tw<512>(tw, twg, tid);
    const float s1 = bnp[c], t1 = bnp[32+c];
    const int row = tid >> 6, l = tid & 63;
    const int o0 = ((l&7)<<3) | (l>>3);
    const float* rp = cvo + ((size_t)bc*512 + h0 + row)*512 + o0;
    float ls = 0.f, lsq = 0.f;
    float2 v[8];
    #pragma unroll
    for (int q = 0; q < 8; ++q) {
        float y = fmaxf(fmaf(rp[64*q], s1, t1), 0.f);
        ls += y; lsq += y*y;
        v[q] = make_float2(y, 0.f);
    }
    dft8<false>(v);
    oct_write(d + row*ROWL, l, v);
    fft_st12<8,512,false>(d, tw, tid);
    for (int i = tid; i < 8*WF; i += 512) {
        int ho = i & 7, w = i >> 3;
        spec[((size_t)bc*WF + w)*512 + h0 + ho] = d[ho*ROWL + LP(w)];
    }
    #pragma unroll
    for (int off = 32; off; off >>= 1){ ls += __shfl_down(ls, off, 64); lsq += __shfl_down(lsq, off, 64); }
    if ((tid & 63) == 0){ red[(tid>>6)*2] = ls; red[(tid>>6)*2+1] = lsq; }
    __syncthreads();
    if (tid == 0) {
        float a = 0.f, b = 0.f;
        #pragma unroll
        for (int i = 0; i < 8; ++i){ a += red[i*2]; b += red[i*2+1]; }
        int bin = blockIdx.x & 63;
        atomicAdd(&ystats[bin*64 + c], a);
        atomicAdd(&ystats[bin*64 + 32 + c], b);
    }
}

// ---------------- col FFT + MLP/gate + inverse col FFT + spectral BN2 sums ----------------
__global__ __launch_bounds__(256) void k_colfft(float2* __restrict__ spec,
    const float* __restrict__ w1, const float* __restrict__ b1,
    const float* __restrict__ w2, const float* __restrict__ b2,
    const float2* __restrict__ twg, float* __restrict__ sstats)
{
    __shared__ float2 tw[512];
    __shared__ float2 d[4*ROWL];
    __shared__ float wl[80];
    __shared__ float red[4][12];
    const int tid = threadIdx.x;
    const int w = blockIdx.x;
    const int k = blockIdx.y;
    const int b = blockIdx.z;
    ld_tw<256>(tw, twg, tid);
    if (tid < 16) {
        wl[tid]      = w1[k*16 + tid];
        wl[16 + tid] = w1[128 + k*16 + tid];
        wl[32 + tid] = w2[k*16 + tid];
        wl[48 + tid] = w2[128 + k*16 + tid];
    } else if (tid < 20) {
        int o = tid - 16;
        wl[64 + o] = b1[k*4 + o];
        wl[68 + o] = b1[32 + k*4 + o];
        wl[72 + o] = b2[k*4 + o];
        wl[76 + o] = b2[32 + k*4 + o];
    }
    const size_t base0 = ((size_t)(b*32 + k*4)*WF + w) * 512;
    const int cc0 = tid >> 6, l = tid & 63;
    const int o0 = ((l&7)<<3) | (l>>3);
    {   // forward stage 0 straight from global (permuted-dense, coalesced)
        const float2* sp = spec + base0 + (size_t)cc0*(WF*512) + o0;
        float2 v[8];
        #pragma unroll
        for (int q = 0; q < 8; ++q) v[q] = sp[64*q];
        dft8<false>(v);
        oct_write(d + cc0*ROWL, l, v);
    }
    fft_st12<4,256,false>(d, tw, tid);
    // MLP + gate at positions ph (in-place z write)
    #pragma unroll
    for (int rep = 0; rep < 2; ++rep) {
        const int ph = LP(rep*256 + tid);
        float xr[4], xi[4];
        #pragma unroll
        for (int i = 0; i < 4; ++i) {
            float2 vv = d[i*ROWL + ph];
            xr[i] = vv.x * (1.f/512.f);
            xi[i] = vv.y * (1.f/512.f);
        }
        float o1r[4], o1i[4];
        #pragma unroll
        for (int o = 0; o < 4; ++o) {
            float sr = wl[64+o], si = wl[68+o];
            #pragma unroll
            for (int i = 0; i < 4; ++i) {
                float wr = wl[i*4+o], wi = wl[16 + i*4+o];
                sr += xr[i]*wr - xi[i]*wi;
                si += xi[i]*wr + xr[i]*wi;
            }
            o1r[o] = fmaxf(sr, 0.f);
            o1i[o] = fmaxf(si, 0.f);
        }
        #pragma unroll
        for (int o = 0; o < 4; ++o) {
            float sr = wl[72+o], si = wl[76+o];
            #pragma unroll
            for (int i = 0; i < 4; ++i) {
                float wr = wl[32 + i*4+o], wi = wl[48 + i*4+o];
                sr += o1r[i]*wr - o1i[i]*wi;
                si += o1i[i]*wr + o1r[i]*wi;
            }
            sr = (sr > LAM) ? sr - LAM : ((sr < -LAM) ? sr + LAM : 0.f);
            si = (si > LAM) ? si - LAM : ((si < -LAM) ? si + LAM : 0.f);
            d[o*ROWL + ph] = make_float2(sr*xr[o] - si*xi[o], sr*xi[o] + si*xr[o]);
        }
    }
    __syncthreads();
    {   // inverse stage 0: gather natural z, dft8, octet write
        float2 v[8];
        oct_gather(d + cc0*ROWL, o0, v);
        dft8<true>(v);
        __syncthreads();
        oct_write(d + cc0*ROWL, l, v);
    }
    fft_st12<4,256,true>(d, tw, tid);
    // epilogue: output write + Parseval sums (re-read u from L1/L2-hot global)
    const bool edge = (w == 0) || (w == 256);
    float fl[12];
    #pragma unroll
    for (int i = 0; i < 12; ++i) fl[i] = 0.f;
    #pragma unroll
    for (int cc = 0; cc < 4; ++cc) {
        float4 uv = ((const float4*)(spec + base0 + (size_t)cc*(WF*512)))[tid];
        float4 vv = *(const float4*)(d + cc*ROWL + LP(2*tid));
        ((float4*)(spec + base0 + (size_t)cc*(WF*512)))[tid] = vv;
        if (edge) {
            fl[cc]   += vv.x*vv.x + vv.z*vv.z;
            fl[4+cc] += vv.x*uv.x + vv.z*uv.z;
            if (w == 0) fl[8+cc] += vv.x + vv.z;
        } else {
            fl[cc]   += 2.f*(vv.x*vv.x + vv.y*vv.y + vv.z*vv.z + vv.w*vv.w);
            fl[4+cc] += 2.f*(vv.x*uv.x + vv.y*uv.y + vv.z*uv.z + vv.w*uv.w);
        }
    }
    #pragma unroll
    for (int i = 0; i < 12; ++i)
        #pragma unroll
        for (int off = 32; off; off >>= 1)
            fl[i] += __shfl_down(fl[i], off, 64);
    const int wid = tid >> 6, lane = tid & 63;
    if (lane == 0)
        #pragma unroll
        for (int i = 0; i < 12; ++i) red[wid][i] = fl[i];
    __syncthreads();
    if (tid < 12) {
        float v = red[0][tid] + red[1][tid] + red[2][tid] + red[3][tid];
        int type = tid >> 2, cc = tid & 3;
        if (type < 2 || w == 0) {
            int bin = (w + b*8 + k) & 31;
            atomicAdd(&sstats[bin*96 + type*32 + k*4 + cc], v);
        }
    }
}

// ---------------- row irfft (W) + residual + BN2 + final ReLU, single write ----------------
__global__ __launch_bounds__(512) void k_rowfft_inv(
    const float2* __restrict__ spec, const float* __restrict__ cvo,
    const float* __restrict__ bnp, const float* __restrict__ bnp2,
    const float2* __restrict__ twg, float* __restrict__ out)
{
    __shared__ float2 tw[512];
    __shared__ float2 d[8*ROWL];
    const int tid = threadIdx.x;
    const int h0 = blockIdx.x * 8;
    const int bc = blockIdx.y;
    const int c = bc & 31;
    ld_tw<512>(tw, twg, tid);
    // natural-order load + Hermitian mirror (linear LDS writes)
    for (int i = tid; i < 8*WF; i += 512) {
        int ho = i & 7, w = i >> 3;
        float2 v = spec[((size_t)bc*WF + w)*512 + h0 + ho];
        d[ho*ROWL + LP(w)] = v;
        if ((unsigned)(w - 1) < 255u)
            d[ho*ROWL + LP(512 - w)] = make_float2(v.x, -v.y);
    }
    __syncthreads();
    const int row = tid >> 6, l = tid & 63;
    const int o0 = ((l&7)<<3) | (l>>3);
    {
        float2 v[8];
        oct_gather(d + row*ROWL, o0, v);
        dft8<true>(v);
        __syncthreads();
        oct_write(d + row*ROWL, l, v);
    }
    fft_st12<8,512,true>(d, tw, tid);
    const float s1 = bnp[c],  t1 = bnp[32+c];
    const float s2 = bnp2[c], t2 = bnp2[32+c];
    #pragma unroll
    for (int r = 0; r < 8; ++r) {
        size_t gi = ((size_t)bc*512 + h0 + r)*512 + tid;
        float cv = cvo[gi];
        float yv = fmaxf(fmaf(cv, s1, t1), 0.f);
        float fo = fmaf(d[r*ROWL + LP(tid)].x, (1.f/512.f), yv);
        out[gi] = fmaxf(yv + fmaf(fo, s2, t2), 0.f);
    }
}

extern "C" void kernel_launch(void* const* d_in, const int* in_sizes, int n_in,
                              void* d_out, int out_size, void* d_ws, size_t ws_size,
                              hipStream_t stream)
{
    const float* x      = (const float*)d_in[0];
    const float* conv_w = (const float*)d_in[1];
    const float* conv_b = (const float*)d_in[2];
    const float* bn1g   = (const float*)d_in[3];
    const float* bn1b   = (const float*)d_in[4];
    const float* w1     = (const float*)d_in[5];
    const float* b1     = (const float*)d_in[6];
    const float* w2     = (const float*)d_in[7];
    const float* b2     = (const float*)d_in[8];
    const float* bn2g   = (const float*)d_in[9];
    const float* bn2b   = (const float*)d_in[10];
    float* out = (float*)d_out;

    char* ws = (char*)d_ws;
    float2* spec  = (float2*)ws;                            // 134,742,016 B
    ushort* xt    = (ushort*)ws;                            // aliases spec (dead before spec written)
    float*  cvo   = (float*)(ws + 134742016);               // 134,217,728 B
    ushort* wtp   = (ushort*)(ws + 134742016 + 134217728);  // 18,432 B
    float*  stats = (float*)(ws + 134742016 + 134217728 + 18432);
    float* stats1 = stats;             // 4096 f (bn1 bins)
    float* ystats = stats + 4096;      // 4096 f
    float* sstats = stats + 8192;      // 3072 f
    float* bnp1   = stats + 11264;     // 64 f
    float* bnp2   = stats + 11328;     // 64 f
    float2* twg   = (float2*)(stats + 11392); // 512 float2

    hipMemsetAsync(stats, 0, 11264*sizeof(float), stream);
    k_twiddle<<<2, 256, 0, stream>>>(twg);
    k_wprep<<<36, 256, 0, stream>>>(conv_w, wtp);
    k_transpose<<<dim3(8,512,4), 256, 0, stream>>>(x, xt);
    k_conv_mfma<<<dim3(8,128,4), 256, 0, stream>>>(xt, wtp, conv_b, cvo, stats1);
    k_finalize<<<1, 64, 0, stream>>>(stats1, 64, bn1g, bn1b, bnp1);
    k_rowfft_fwd<<<dim3(64,128), 512, 0, stream>>>(cvo, bnp1, twg, spec, ystats);
    k_colfft<<<dim3(257,8,4), 256, 0, stream>>>(spec, w1, b1, w2, b2, twg, sstats);
    k_finalize2<<<1, 64, 0, stream>>>(ystats, sstats, bn2g, bn2b, bnp2);
    k_rowfft_inv<<<dim3(64,128), 512, 0, stream>>>(spec, cvo, bnp1, bnp2, twg, out);
}

// Round 6
// 374.795 us; speedup vs baseline: 1.3163x; 1.1571x over previous
//
#include <hip/hip_runtime.h>

#define WF 257
#define LAM 0.01f
#define ROWL 588
#define LP(i) ((i) + (((i)>>4)<<1) + (((i)>>6)<<1))

typedef __attribute__((ext_vector_type(8))) short short8;
typedef __attribute__((ext_vector_type(4))) float f32x4;

__device__ __forceinline__ ushort f2bf(float f){
    unsigned u = __float_as_uint(f);
    unsigned r = (u + 0x7fffu + ((u >> 16) & 1u)) >> 16;
    return (ushort)r;
}
__device__ __forceinline__ float bf2f(ushort u){ return __uint_as_float((uint)u << 16); }
__device__ __forceinline__ uint packbf(float a, float b){
    return (uint)f2bf(a) | ((uint)f2bf(b) << 16);
}
__device__ __forceinline__ float2 unpackbf(uint u){
    return make_float2(__uint_as_float(u << 16), __uint_as_float(u & 0xffff0000u));
}

__device__ __forceinline__ float2 cmul(float2 a, float2 b){
    return make_float2(a.x*b.x - a.y*b.y, a.x*b.y + a.y*b.x);
}
__device__ __forceinline__ float2 cadd(float2 a, float2 b){ return make_float2(a.x+b.x, a.y+b.y); }
__device__ __forceinline__ float2 csub(float2 a, float2 b){ return make_float2(a.x-b.x, a.y-b.y); }

template<int NTHREADS>
__device__ __forceinline__ void ld_tw(float2* tw, const float2* __restrict__ twg, int tid){
    for (int t = tid; t < 256; t += NTHREADS)
        ((float4*)tw)[t] = ((const float4*)twg)[t];
}

template<bool INV>
__device__ __forceinline__ float2 twz(const float2* tw, int idx){
    float2 w = tw[idx];
    if (INV) w.y = -w.y;
    return w;
}

template<bool INV>
__device__ __forceinline__ void dft8(float2 v[8]) {
    const float R = 0.70710678118654752f;
    float2 y0=v[0], y1=v[4], y2=v[2], y3=v[6], y4=v[1], y5=v[5], y6=v[3], y7=v[7];
    float2 t;
    t=y1; y1=csub(y0,t); y0=cadd(y0,t);
    t=y3; y3=csub(y2,t); y2=cadd(y2,t);
    t=y5; y5=csub(y4,t); y4=cadd(y4,t);
    t=y7; y7=csub(y6,t); y6=cadd(y6,t);
    t=y2; y2=csub(y0,t); y0=cadd(y0,t);
    t = INV ? make_float2(-y3.y, y3.x) : make_float2(y3.y, -y3.x);
    y3=csub(y1,t); y1=cadd(y1,t);
    t=y6; y6=csub(y4,t); y4=cadd(y4,t);
    t = INV ? make_float2(-y7.y, y7.x) : make_float2(y7.y, -y7.x);
    y7=csub(y5,t); y5=cadd(y5,t);
    t=y4; y4=csub(y0,t); y0=cadd(y0,t);
    { float2 w8 = INV ? make_float2(R, R) : make_float2(R,-R);
      t=cmul(y5,w8); y5=csub(y1,t); y1=cadd(y1,t); }
    t = INV ? make_float2(-y6.y, y6.x) : make_float2(y6.y, -y6.x);
    y6=csub(y2,t); y2=cadd(y2,t);
    { float2 w8 = INV ? make_float2(-R, R) : make_float2(-R,-R);
      t=cmul(y7,w8); y7=csub(y3,t); y3=cadd(y3,t); }
    v[0]=y0; v[1]=y1; v[2]=y2; v[3]=y3; v[4]=y4; v[5]=y5; v[6]=y6; v[7]=y7;
}

__device__ __forceinline__ void oct_write(float2* drow, int l, const float2 v[8]){
    float4* p = (float4*)(drow + LP(8*l));
    p[0]=make_float4(v[0].x,v[0].y,v[1].x,v[1].y);
    p[1]=make_float4(v[2].x,v[2].y,v[3].x,v[3].y);
    p[2]=make_float4(v[4].x,v[4].y,v[5].x,v[5].y);
    p[3]=make_float4(v[6].x,v[6].y,v[7].x,v[7].y);
}

__device__ __forceinline__ void oct_gather(const float2* drow, int o0, float2 v[8]){
    const float2* b = drow + LP(o0);        // LP(o0+64q) == LP(o0) + 74q
    #pragma unroll
    for (int q = 0; q < 8; ++q) v[q] = b[74*q];
}

template<int NROWS, int NTHREADS, bool INV>
__device__ __forceinline__ void fft_st12(float2* d, const float2* tw, int tid)
{
    __syncthreads();
    #pragma unroll
    for (int rep = 0; rep < (NROWS*64)/NTHREADS; ++rep){
        int slot = rep*NTHREADS + tid;
        int row = slot>>6, l = slot&63;
        int a = l&7, m = l>>3;
        float2* b = d + row*ROWL + 74*m + a;
        float2 v[8];
        v[0] = b[0];
        v[1] = cmul(b[8],  twz<INV>(tw, 8*a));
        v[2] = cmul(b[18], twz<INV>(tw, 16*a));
        v[3] = cmul(b[26], twz<INV>(tw, 24*a));
        v[4] = cmul(b[36], twz<INV>(tw, 32*a));
        v[5] = cmul(b[44], twz<INV>(tw, 40*a));
        v[6] = cmul(b[54], twz<INV>(tw, 48*a));
        v[7] = cmul(b[62], twz<INV>(tw, 56*a));
        dft8<INV>(v);
        b[0]=v[0]; b[8]=v[1]; b[18]=v[2]; b[26]=v[3]; b[36]=v[4]; b[44]=v[5]; b[54]=v[6]; b[62]=v[7];
    }
    __syncthreads();
    #pragma unroll
    for (int rep = 0; rep < (NROWS*64)/NTHREADS; ++rep){
        int slot = rep*NTHREADS + tid;
        int row = slot>>6, l = slot&63;
        float2* b = d + row*ROWL + l + 2*(l>>4);
        float2 v[8];
        v[0] = b[0];
        #pragma unroll
        for (int q = 1; q < 8; ++q)
            v[q] = cmul(b[74*q], twz<INV>(tw, (l*q)&511));
        dft8<INV>(v);
        #pragma unroll
        for (int q = 0; q < 8; ++q) b[74*q] = v[q];
    }
    __syncthreads();
}

__global__ void k_twiddle(float2* __restrict__ twg){
    int t = blockIdx.x*256 + threadIdx.x;
    if (t < 512) {
        float s, c;
        sincosf((float)t * (-6.2831853071795864769f/512.0f), &s, &c);
        twg[t] = make_float2(c, s);
    }
}

__global__ void k_wprep(const float* __restrict__ w, ushort* __restrict__ wtp){
    int i = blockIdx.x*256 + threadIdx.x;
    if (i < 9216) {
        int j = i & 7, l = (i>>3) & 63, m = (i>>9) & 1, tap = i >> 10;
        int co = m*16 + (l & 15), ci = ((l>>4)&3)*8 + j;
        wtp[i] = f2bf(w[(co*32 + ci)*9 + tap]);
    }
}

// ---------------- NCHW fp32 -> NHWC bf16 transpose ----------------
__global__ __launch_bounds__(256) void k_transpose(const float* __restrict__ x, ushort* __restrict__ xt){
    __shared__ ushort tl[64][36];
    const int tid = threadIdx.x;
    const int w0 = blockIdx.x*64, h = blockIdx.y, b = blockIdx.z;
    #pragma unroll
    for (int it = 0; it < 8; ++it) {
        int i = it*256 + tid, c = i >> 6, ww = i & 63;
        tl[ww][c] = f2bf(x[(((size_t)b*32 + c)*512 + h)*512 + w0 + ww]);
    }
    __syncthreads();
    const int ww = tid >> 2, c0 = (tid & 3) * 8;
    uint4 v;
    v.x = *(const uint*)&tl[ww][c0+0];
    v.y = *(const uint*)&tl[ww][c0+2];
    v.z = *(const uint*)&tl[ww][c0+4];
    v.w = *(const uint*)&tl[ww][c0+6];
    *(uint4*)(xt + ((((size_t)b*512 + h)*512 + w0 + ww)*32 + c0)) = v;
}

// ---------------- conv 3x3 via bf16 MFMA, bf16 out, fused bias + BN1 stats ----------------
__global__ __launch_bounds__(256) void k_conv_mfma(
    const ushort* __restrict__ xt, const ushort* __restrict__ wtp,
    const float* __restrict__ bias, ushort* __restrict__ out, float* __restrict__ stats)
{
    __shared__ float sred[64];
    const int tid = threadIdx.x;
    const int wid = tid >> 6, lane = tid & 63;
    const int h = blockIdx.y*4 + wid;
    const int w0 = blockIdx.x*64;
    const int b = blockIdx.z;

    short8 wa[9][2];
    #pragma unroll
    for (int tap = 0; tap < 9; ++tap)
        #pragma unroll
        for (int m = 0; m < 2; ++m)
            wa[tap][m] = *reinterpret_cast<const short8*>(wtp + ((tap*2 + m)*64 + lane)*8);

    f32x4 acc[2][4];
    #pragma unroll
    for (int m = 0; m < 2; ++m)
        #pragma unroll
        for (int n = 0; n < 4; ++n)
            acc[m][n] = (f32x4){0.f, 0.f, 0.f, 0.f};

    const int c0 = ((lane >> 4) & 3) * 8;
    const int pw = w0 + (lane & 15);
    const size_t ibase = (size_t)b * 512 * 512;

    #pragma unroll
    for (int dy = -1; dy <= 1; ++dy) {
        const int hh = h + dy;
        const bool hok = (unsigned)hh < 512u;
        #pragma unroll
        for (int dx = -1; dx <= 1; ++dx) {
            const int tap = (dy+1)*3 + (dx+1);
            short8 bfr[4];
            #pragma unroll
            for (int n = 0; n < 4; ++n) {
                const int ww = pw + n*16 + dx;
                short8 v = {0,0,0,0,0,0,0,0};
                if (hok && (unsigned)ww < 512u)
                    v = *reinterpret_cast<const short8*>(xt + ((ibase + (size_t)hh*512 + ww)*32 + c0));
                bfr[n] = v;
            }
            #pragma unroll
            for (int m = 0; m < 2; ++m)
                #pragma unroll
                for (int n = 0; n < 4; ++n)
                    acc[m][n] = __builtin_amdgcn_mfma_f32_16x16x32_bf16(wa[tap][m], bfr[n], acc[m][n], 0, 0, 0);
        }
    }

    if (tid < 64) sred[tid] = 0.f;
    __syncthreads();

    float bv[2][4];
    #pragma unroll
    for (int m = 0; m < 2; ++m)
        #pragma unroll
        for (int r = 0; r < 4; ++r)
            bv[m][r] = bias[m*16 + ((lane>>4)&3)*4 + r];

    float s8[8], q8[8];
    #pragma unroll
    for (int i = 0; i < 8; ++i) { s8[i] = 0.f; q8[i] = 0.f; }

    #pragma unroll
    for (int m = 0; m < 2; ++m) {
        #pragma unroll
        for (int n = 0; n < 4; ++n) {
            #pragma unroll
            for (int r = 0; r < 4; ++r) {
                const int co = m*16 + ((lane>>4)&3)*4 + r;
                const int ww = w0 + n*16 + (lane & 15);
                float val = acc[m][n][r] + bv[m][r];
                out[(((size_t)b*32 + co)*512 + h)*512 + ww] = f2bf(val);
                s8[m*4+r] += val;
                q8[m*4+r] += val*val;
            }
        }
    }
    #pragma unroll
    for (int i = 0; i < 8; ++i) {
        #pragma unroll
        for (int off = 1; off < 16; off <<= 1) {
            s8[i] += __shfl_xor(s8[i], off, 64);
            q8[i] += __shfl_xor(q8[i], off, 64);
        }
    }
    if ((lane & 15) == 0) {
        #pragma unroll
        for (int m = 0; m < 2; ++m)
            #pragma unroll
            for (int r = 0; r < 4; ++r) {
                const int co = m*16 + ((lane>>4)&3)*4 + r;
                atomicAdd(&sred[co], s8[m*4+r]);
                atomicAdd(&sred[32+co], q8[m*4+r]);
            }
    }
    __syncthreads();
    if (tid < 64) {
        int bin = (blockIdx.y*8 + blockIdx.x + blockIdx.z) & 63;
        atomicAdd(&stats[bin*64 + tid], sred[tid]);
    }
}

__global__ void k_finalize(const float* __restrict__ stats, int nbins, const float* __restrict__ g,
                           const float* __restrict__ bta, float* __restrict__ bnp)
{
    int c = threadIdx.x;
    if (c < 32) {
        float s = 0.f, q = 0.f;
        for (int i = 0; i < nbins; ++i) { s += stats[i*64 + c]; q += stats[i*64 + 32 + c]; }
        const float inv_n = 1.f/1048576.f;
        float mean = s * inv_n;
        float var  = q * inv_n - mean*mean;
        float sc = g[c] * rsqrtf(var + 1e-5f);
        bnp[c] = sc;
        bnp[32+c] = bta[c] - mean*sc;
    }
}

__global__ void k_finalize2(const float* __restrict__ ystats, const float* __restrict__ sstats,
                            const float* __restrict__ g, const float* __restrict__ bta,
                            float* __restrict__ bnp2)
{
    int c = threadIdx.x;
    if (c < 32) {
        float Sy = 0.f, Sy2 = 0.f, Sgg = 0.f, Sgu = 0.f, Sg0 = 0.f;
        for (int i = 0; i < 64; ++i){ Sy  += ystats[i*64 + c]; Sy2 += ystats[i*64 + 32 + c]; }
        for (int i = 0; i < 32; ++i){ Sgg += sstats[i*96 + c]; Sgu += sstats[i*96 + 32 + c]; Sg0 += sstats[i*96 + 64 + c]; }
        const float inv_n = 1.f/1048576.f;
        float Sfo  = Sg0 + Sy;
        float Sfo2 = Sgg*(1.f/512.f) + Sgu*(2.f/512.f) + Sy2;
        float mean = Sfo*inv_n;
        float var  = Sfo2*inv_n - mean*mean;
        float sc = g[c]*rsqrtf(var + 1e-5f);
        bnp2[c] = sc;
        bnp2[32+c] = bta[c] - mean*sc;
    }
}

// ---------------- row rfft: 2 real rows per complex FFT, bf16 in/out ----------------
__global__ __launch_bounds__(512) void k_rowfft_fwd(
    const ushort* __restrict__ cvo, const float* __restrict__ bnp,
    const float2* __restrict__ twg, uint* __restrict__ spec, float* __restrict__ ystats)
{
    __shared__ float2 tw[512];
    __shared__ float2 d[8*ROWL];
    __shared__ float red[16];
    const int tid = threadIdx.x;
    const int h0 = blockIdx.x * 16;
    const int bc = blockIdx.y;
    const int c = bc & 31;
    ld_tw<512>(tw, twg, tid);
    const float s1 = bnp[c], t1 = bnp[32+c];
    const int row = tid >> 6, l = tid & 63;
    const int o0 = ((l&7)<<3) | (l>>3);
    const ushort* rp0 = cvo + ((size_t)bc*512 + h0 + 2*row)*512 + o0;
    const ushort* rp1 = rp0 + 512;
    float ls = 0.f, lsq = 0.f;
    float2 v[8];
    #pragma unroll
    for (int q = 0; q < 8; ++q) {
        float y0 = fmaxf(fmaf(bf2f(rp0[64*q]), s1, t1), 0.f);
        float y1 = fmaxf(fmaf(bf2f(rp1[64*q]), s1, t1), 0.f);
        ls += y0 + y1; lsq += y0*y0 + y1*y1;
        v[q] = make_float2(y0, y1);
    }
    dft8<false>(v);
    oct_write(d + row*ROWL, l, v);
    fft_st12<8,512,false>(d, tw, tid);
    // Hermitian split: rows (2p, 2p+1) from complex FFT p
    for (int i = tid; i < 8*WF; i += 512) {
        int p = i & 7, w = i >> 3;
        float2 Z  = d[p*ROWL + LP(w)];
        float2 Zm = d[p*ROWL + LP((512 - w) & 511)];
        float x1r = 0.5f*(Z.x + Zm.x), x1i = 0.5f*(Z.y - Zm.y);
        float x2r = 0.5f*(Z.y + Zm.y), x2i = 0.5f*(Zm.x - Z.x);
        uint2 pk;
        pk.x = packbf(x1r, x1i);
        pk.y = packbf(x2r, x2i);
        *(uint2*)(spec + ((size_t)bc*WF + w)*512 + h0 + 2*p) = pk;
    }
    #pragma unroll
    for (int off = 32; off; off >>= 1){ ls += __shfl_down(ls, off, 64); lsq += __shfl_down(lsq, off, 64); }
    if ((tid & 63) == 0){ red[(tid>>6)*2] = ls; red[(tid>>6)*2+1] = lsq; }
    __syncthreads();
    if (tid == 0) {
        float a = 0.f, b = 0.f;
        #pragma unroll
        for (int i = 0; i < 8; ++i){ a += red[i*2]; b += red[i*2+1]; }
        int bin = blockIdx.x & 63;
        atomicAdd(&ystats[bin*64 + c], a);
        atomicAdd(&ystats[bin*64 + 32 + c], b);
    }
}

// ---------------- col FFT + MLP/gate + inverse col FFT + Parseval sums (bf16 spec) ----------------
__global__ __launch_bounds__(256) void k_colfft(uint* __restrict__ spec,
    const float* __restrict__ w1, const float* __restrict__ b1,
    const float* __restrict__ w2, const float* __restrict__ b2,
    const float2* __restrict__ twg, float* __restrict__ sstats)
{
    __shared__ float2 tw[512];
    __shared__ float2 d[4*ROWL];
    __shared__ float wl[80];
    __shared__ float red[4][12];
    const int tid = threadIdx.x;
    const int w = blockIdx.x;
    const int k = blockIdx.y;
    const int b = blockIdx.z;
    ld_tw<256>(tw, twg, tid);
    if (tid < 16) {
        wl[tid]      = w1[k*16 + tid];
        wl[16 + tid] = w1[128 + k*16 + tid];
        wl[32 + tid] = w2[k*16 + tid];
        wl[48 + tid] = w2[128 + k*16 + tid];
    } else if (tid < 20) {
        int o = tid - 16;
        wl[64 + o] = b1[k*4 + o];
        wl[68 + o] = b1[32 + k*4 + o];
        wl[72 + o] = b2[k*4 + o];
        wl[76 + o] = b2[32 + k*4 + o];
    }
    const size_t base0 = ((size_t)(b*32 + k*4)*WF + w) * 512;
    const int cc0 = tid >> 6, l = tid & 63;
    const int o0 = ((l&7)<<3) | (l>>3);
    {
        const uint* sp = spec + base0 + (size_t)cc0*(WF*512) + o0;
        float2 v[8];
        #pragma unroll
        for (int q = 0; q < 8; ++q) v[q] = unpackbf(sp[64*q]);
        dft8<false>(v);
        oct_write(d + cc0*ROWL, l, v);
    }
    fft_st12<4,256,false>(d, tw, tid);
    #pragma unroll
    for (int rep = 0; rep < 2; ++rep) {
        const int ph = LP(rep*256 + tid);
        float xr[4], xi[4];
        #pragma unroll
        for (int i = 0; i < 4; ++i) {
            float2 vv = d[i*ROWL + ph];
            xr[i] = vv.x * (1.f/512.f);
            xi[i] = vv.y * (1.f/512.f);
        }
        float o1r[4], o1i[4];
        #pragma unroll
        for (int o = 0; o < 4; ++o) {
            float sr = wl[64+o], si = wl[68+o];
            #pragma unroll
            for (int i = 0; i < 4; ++i) {
                float wr = wl[i*4+o], wi = wl[16 + i*4+o];
                sr += xr[i]*wr - xi[i]*wi;
                si += xi[i]*wr + xr[i]*wi;
            }
            o1r[o] = fmaxf(sr, 0.f);
            o1i[o] = fmaxf(si, 0.f);
        }
        #pragma unroll
        for (int o = 0; o < 4; ++o) {
            float sr = wl[72+o], si = wl[76+o];
            #pragma unroll
            for (int i = 0; i < 4; ++i) {
                float wr = wl[32 + i*4+o], wi = wl[48 + i*4+o];
                sr += o1r[i]*wr - o1i[i]*wi;
                si += o1i[i]*wr + o1r[i]*wi;
            }
            sr = (sr > LAM) ? sr - LAM : ((sr < -LAM) ? sr + LAM : 0.f);
            si = (si > LAM) ? si - LAM : ((si < -LAM) ? si + LAM : 0.f);
            d[o*ROWL + ph] = make_float2(sr*xr[o] - si*xi[o], sr*xi[o] + si*xr[o]);
        }
    }
    __syncthreads();
    {
        float2 v[8];
        oct_gather(d + cc0*ROWL, o0, v);
        dft8<true>(v);
        __syncthreads();
        oct_write(d + cc0*ROWL, l, v);
    }
    fft_st12<4,256,true>(d, tw, tid);
    const bool edge = (w == 0) || (w == 256);
    float fl[12];
    #pragma unroll
    for (int i = 0; i < 12; ++i) fl[i] = 0.f;
    #pragma unroll
    for (int cc = 0; cc < 4; ++cc) {
        uint2 up = *(const uint2*)(spec + base0 + (size_t)cc*(WF*512) + 2*tid);
        float2 u0 = unpackbf(up.x), u1 = unpackbf(up.y);
        float4 vv = *(const float4*)(d + cc*ROWL + LP(2*tid));
        uint2 gp;
        gp.x = packbf(vv.x, vv.y);
        gp.y = packbf(vv.z, vv.w);
        *(uint2*)(spec + base0 + (size_t)cc*(WF*512) + 2*tid) = gp;
        float2 g0 = unpackbf(gp.x), g1 = unpackbf(gp.y);   // rounded values (consistent with storage)
        if (edge) {
            fl[cc]   += g0.x*g0.x + g1.x*g1.x;
            fl[4+cc] += g0.x*u0.x + g1.x*u1.x;
            if (w == 0) fl[8+cc] += g0.x + g1.x;
        } else {
            fl[cc]   += 2.f*(g0.x*g0.x + g0.y*g0.y + g1.x*g1.x + g1.y*g1.y);
            fl[4+cc] += 2.f*(g0.x*u0.x + g0.y*u0.y + g1.x*u1.x + g1.y*u1.y);
        }
    }
    #pragma unroll
    for (int i = 0; i < 12; ++i)
        #pragma unroll
        for (int off = 32; off; off >>= 1)
            fl[i] += __shfl_down(fl[i], off, 64);
    const int wid = tid >> 6, lane = tid & 63;
    if (lane == 0)
        #pragma unroll
        for (int i = 0; i < 12; ++i) red[wid][i] = fl[i];
    __syncthreads();
    if (tid < 12) {
        float v = red[0][tid] + red[1][tid] + red[2][tid] + red[3][tid];
        int type = tid >> 2, cc = tid & 3;
        if (type < 2 || w == 0) {
            int bin = (w + b*8 + k) & 31;
            atomicAdd(&sstats[bin*96 + type*32 + k*4 + cc], v);
        }
    }
}

// ---------------- row irfft: 2 real rows per complex inverse FFT + BN2 + final ReLU ----------------
__global__ __launch_bounds__(512) void k_rowfft_inv(
    const uint* __restrict__ spec, const ushort* __restrict__ cvo,
    const float* __restrict__ bnp, const float* __restrict__ bnp2,
    const float2* __restrict__ twg, float* __restrict__ out)
{
    __shared__ float2 tw[512];
    __shared__ float2 d[8*ROWL];
    const int tid = threadIdx.x;
    const int h0 = blockIdx.x * 16;
    const int bc = blockIdx.y;
    const int c = bc & 31;
    ld_tw<512>(tw, twg, tid);
    for (int i = tid; i < 8*WF; i += 512) {
        int p = i & 7, w = i >> 3;
        uint2 pk = *(const uint2*)(spec + ((size_t)bc*WF + w)*512 + h0 + 2*p);
        float2 X1 = unpackbf(pk.x), X2 = unpackbf(pk.y);
        if (w == 0 || w == 256) { X1.y = 0.f; X2.y = 0.f; }   // irfft drops imag at DC/Nyquist
        d[p*ROWL + LP(w)] = make_float2(X1.x - X2.y, X1.y + X2.x);
        if ((unsigned)(w - 1) < 255u)
            d[p*ROWL + LP(512 - w)] = make_float2(X1.x + X2.y, X2.x - X1.y);
    }
    __syncthreads();
    const int row = tid >> 6, l = tid & 63;
    const int o0 = ((l&7)<<3) | (l>>3);
    {
        float2 v[8];
        oct_gather(d + row*ROWL, o0, v);
        dft8<true>(v);
        __syncthreads();
        oct_write(d + row*ROWL, l, v);
    }
    fft_st12<8,512,true>(d, tw, tid);
    const float s1 = bnp[c],  t1 = bnp[32+c];
    const float s2 = bnp2[c], t2 = bnp2[32+c];
    #pragma unroll
    for (int p = 0; p < 8; ++p) {
        float2 v = d[p*ROWL + LP(tid)];
        size_t g0 = ((size_t)bc*512 + h0 + 2*p)*512 + tid;
        float y0 = fmaxf(fmaf(bf2f(cvo[g0]), s1, t1), 0.f);
        float fo0 = fmaf(v.x, (1.f/512.f), y0);
        out[g0] = fmaxf(y0 + fmaf(fo0, s2, t2), 0.f);
        float y1 = fmaxf(fmaf(bf2f(cvo[g0 + 512]), s1, t1), 0.f);
        float fo1 = fmaf(v.y, (1.f/512.f), y1);
        out[g0 + 512] = fmaxf(y1 + fmaf(fo1, s2, t2), 0.f);
    }
}

extern "C" void kernel_launch(void* const* d_in, const int* in_sizes, int n_in,
                              void* d_out, int out_size, void* d_ws, size_t ws_size,
                              hipStream_t stream)
{
    const float* x      = (const float*)d_in[0];
    const float* conv_w = (const float*)d_in[1];
    const float* conv_b = (const float*)d_in[2];
    const float* bn1g   = (const float*)d_in[3];
    const float* bn1b   = (const float*)d_in[4];
    const float* w1     = (const float*)d_in[5];
    const float* b1     = (const float*)d_in[6];
    const float* w2     = (const float*)d_in[7];
    const float* b2     = (const float*)d_in[8];
    const float* bn2g   = (const float*)d_in[9];
    const float* bn2b   = (const float*)d_in[10];
    float* out = (float*)d_out;

    char* ws = (char*)d_ws;
    uint*   spec  = (uint*)ws;                              // 67,371,008 B (bf16 pairs)
    ushort* xt    = (ushort*)ws;                            // 67,108,864 B (aliases spec; dead before spec written)
    ushort* cvo   = (ushort*)(ws + 67371008);               // 67,108,864 B (bf16)
    ushort* wtp   = (ushort*)(ws + 67371008 + 67108864);    // 18,432 B
    float*  stats = (float*)(ws + 67371008 + 67108864 + 18432);
    float* stats1 = stats;             // 4096 f (bn1 bins)
    float* ystats = stats + 4096;      // 4096 f
    float* sstats = stats + 8192;      // 3072 f
    float* bnp1   = stats + 11264;     // 64 f
    float* bnp2   = stats + 11328;     // 64 f
    float2* twg   = (float2*)(stats + 11392); // 512 float2

    hipMemsetAsync(stats, 0, 11264*sizeof(float), stream);
    k_twiddle<<<2, 256, 0, stream>>>(twg);
    k_wprep<<<36, 256, 0, stream>>>(conv_w, wtp);
    k_transpose<<<dim3(8,512,4), 256, 0, stream>>>(x, xt);
    k_conv_mfma<<<dim3(8,128,4), 256, 0, stream>>>(xt, wtp, conv_b, cvo, stats1);
    k_finalize<<<1, 64, 0, stream>>>(stats1, 64, bn1g, bn1b, bnp1);
    k_rowfft_fwd<<<dim3(32,128), 512, 0, stream>>>(cvo, bnp1, twg, spec, ystats);
    k_colfft<<<dim3(257,8,4), 256, 0, stream>>>(spec, w1, b1, w2, b2, twg, sstats);
    k_finalize2<<<1, 64, 0, stream>>>(ystats, sstats, bn2g, bn2b, bnp2);
    k_rowfft_inv<<<dim3(32,128), 512, 0, stream>>>(spec, cvo, bnp1, bnp2, twg, out);
}

// Round 7
// 350.102 us; speedup vs baseline: 1.4092x; 1.0705x over previous
//
#include <hip/hip_runtime.h>

#define WF 257
#define LAM 0.01f
#define ROWL 588
#define LP(i) ((i) + (((i)>>4)<<1) + (((i)>>6)<<1))

// compiler fence + wave scheduling barrier: intra-wave LDS phase handoff
#define WSYNC() do { asm volatile("" ::: "memory"); __builtin_amdgcn_wave_barrier(); asm volatile("" ::: "memory"); } while(0)

typedef __attribute__((ext_vector_type(8))) short short8;
typedef __attribute__((ext_vector_type(4))) float f32x4;

__device__ __forceinline__ ushort f2bf(float f){
    unsigned u = __float_as_uint(f);
    unsigned r = (u + 0x7fffu + ((u >> 16) & 1u)) >> 16;
    return (ushort)r;
}
__device__ __forceinline__ float bf2f(ushort u){ return __uint_as_float((uint)u << 16); }
__device__ __forceinline__ uint packbf(float a, float b){
    return (uint)f2bf(a) | ((uint)f2bf(b) << 16);
}
__device__ __forceinline__ float2 unpackbf(uint u){
    return make_float2(__uint_as_float(u << 16), __uint_as_float(u & 0xffff0000u));
}

__device__ __forceinline__ float2 cmul(float2 a, float2 b){
    return make_float2(a.x*b.x - a.y*b.y, a.x*b.y + a.y*b.x);
}
__device__ __forceinline__ float2 cadd(float2 a, float2 b){ return make_float2(a.x+b.x, a.y+b.y); }
__device__ __forceinline__ float2 csub(float2 a, float2 b){ return make_float2(a.x-b.x, a.y-b.y); }

template<int NTHREADS>
__device__ __forceinline__ void ld_tw(float2* tw, const float2* __restrict__ twg, int tid){
    for (int t = tid; t < 256; t += NTHREADS)
        ((float4*)tw)[t] = ((const float4*)twg)[t];
}

template<bool INV>
__device__ __forceinline__ float2 twz(const float2* tw, int idx){
    float2 w = tw[idx];
    if (INV) w.y = -w.y;
    return w;
}

template<bool INV>
__device__ __forceinline__ void dft8(float2 v[8]) {
    const float R = 0.70710678118654752f;
    float2 y0=v[0], y1=v[4], y2=v[2], y3=v[6], y4=v[1], y5=v[5], y6=v[3], y7=v[7];
    float2 t;
    t=y1; y1=csub(y0,t); y0=cadd(y0,t);
    t=y3; y3=csub(y2,t); y2=cadd(y2,t);
    t=y5; y5=csub(y4,t); y4=cadd(y4,t);
    t=y7; y7=csub(y6,t); y6=cadd(y6,t);
    t=y2; y2=csub(y0,t); y0=cadd(y0,t);
    t = INV ? make_float2(-y3.y, y3.x) : make_float2(y3.y, -y3.x);
    y3=csub(y1,t); y1=cadd(y1,t);
    t=y6; y6=csub(y4,t); y4=cadd(y4,t);
    t = INV ? make_float2(-y7.y, y7.x) : make_float2(y7.y, -y7.x);
    y7=csub(y5,t); y5=cadd(y5,t);
    t=y4; y4=csub(y0,t); y0=cadd(y0,t);
    { float2 w8 = INV ? make_float2(R, R) : make_float2(R,-R);
      t=cmul(y5,w8); y5=csub(y1,t); y1=cadd(y1,t); }
    t = INV ? make_float2(-y6.y, y6.x) : make_float2(y6.y, -y6.x);
    y6=csub(y2,t); y2=cadd(y2,t);
    { float2 w8 = INV ? make_float2(-R, R) : make_float2(-R,-R);
      t=cmul(y7,w8); y7=csub(y3,t); y3=cadd(y3,t); }
    v[0]=y0; v[1]=y1; v[2]=y2; v[3]=y3; v[4]=y4; v[5]=y5; v[6]=y6; v[7]=y7;
}

__device__ __forceinline__ void oct_write(float2* drow, int l, const float2 v[8]){
    float4* p = (float4*)(drow + LP(8*l));
    p[0]=make_float4(v[0].x,v[0].y,v[1].x,v[1].y);
    p[1]=make_float4(v[2].x,v[2].y,v[3].x,v[3].y);
    p[2]=make_float4(v[4].x,v[4].y,v[5].x,v[5].y);
    p[3]=make_float4(v[6].x,v[6].y,v[7].x,v[7].y);
}

__device__ __forceinline__ void oct_gather(const float2* drow, int o0, float2 v[8]){
    const float2* b = drow + LP(o0);        // LP(o0+64q) == LP(o0) + 74q
    #pragma unroll
    for (int q = 0; q < 8; ++q) v[q] = b[74*q];
}

// stages 1+2 of a 512-pt FFT on ONE wave's private row. No block barriers.
template<bool INV>
__device__ __forceinline__ void fft_wave12(float2* drow, const float2* tw, int l)
{
    WSYNC();
    {
        int a = l&7, m = l>>3;
        float2* b = drow + 74*m + a;
        float2 v[8];
        v[0] = b[0];
        v[1] = cmul(b[8],  twz<INV>(tw, 8*a));
        v[2] = cmul(b[18], twz<INV>(tw, 16*a));
        v[3] = cmul(b[26], twz<INV>(tw, 24*a));
        v[4] = cmul(b[36], twz<INV>(tw, 32*a));
        v[5] = cmul(b[44], twz<INV>(tw, 40*a));
        v[6] = cmul(b[54], twz<INV>(tw, 48*a));
        v[7] = cmul(b[62], twz<INV>(tw, 56*a));
        dft8<INV>(v);
        b[0]=v[0]; b[8]=v[1]; b[18]=v[2]; b[26]=v[3]; b[36]=v[4]; b[44]=v[5]; b[54]=v[6]; b[62]=v[7];
    }
    WSYNC();
    {
        float2* b = drow + l + 2*(l>>4);
        float2 v[8];
        v[0] = b[0];
        #pragma unroll
        for (int q = 1; q < 8; ++q)
            v[q] = cmul(b[74*q], twz<INV>(tw, (l*q)&511));
        dft8<INV>(v);
        #pragma unroll
        for (int q = 0; q < 8; ++q) b[74*q] = v[q];
    }
    WSYNC();
}

__global__ void k_twiddle(float2* __restrict__ twg){
    int t = blockIdx.x*256 + threadIdx.x;
    if (t < 512) {
        float s, c;
        sincosf((float)t * (-6.2831853071795864769f/512.0f), &s, &c);
        twg[t] = make_float2(c, s);
    }
}

__global__ void k_wprep(const float* __restrict__ w, ushort* __restrict__ wtp){
    int i = blockIdx.x*256 + threadIdx.x;
    if (i < 9216) {
        int j = i & 7, l = (i>>3) & 63, m = (i>>9) & 1, tap = i >> 10;
        int co = m*16 + (l & 15), ci = ((l>>4)&3)*8 + j;
        wtp[i] = f2bf(w[(co*32 + ci)*9 + tap]);
    }
}

// ---------------- NCHW fp32 -> NHWC bf16 transpose ----------------
__global__ __launch_bounds__(256) void k_transpose(const float* __restrict__ x, ushort* __restrict__ xt){
    __shared__ ushort tl[64][36];
    const int tid = threadIdx.x;
    const int w0 = blockIdx.x*64, h = blockIdx.y, b = blockIdx.z;
    #pragma unroll
    for (int it = 0; it < 8; ++it) {
        int i = it*256 + tid, c = i >> 6, ww = i & 63;
        tl[ww][c] = f2bf(x[(((size_t)b*32 + c)*512 + h)*512 + w0 + ww]);
    }
    __syncthreads();
    const int ww = tid >> 2, c0 = (tid & 3) * 8;
    uint4 v;
    v.x = *(const uint*)&tl[ww][c0+0];
    v.y = *(const uint*)&tl[ww][c0+2];
    v.z = *(const uint*)&tl[ww][c0+4];
    v.w = *(const uint*)&tl[ww][c0+6];
    *(uint4*)(xt + ((((size_t)b*512 + h)*512 + w0 + ww)*32 + c0)) = v;
}

// ---------------- conv 3x3 via bf16 MFMA, bf16 out, fused bias + BN1 stats ----------------
__global__ __launch_bounds__(256) void k_conv_mfma(
    const ushort* __restrict__ xt, const ushort* __restrict__ wtp,
    const float* __restrict__ bias, ushort* __restrict__ out, float* __restrict__ stats)
{
    __shared__ float sred[64];
    const int tid = threadIdx.x;
    const int wid = tid >> 6, lane = tid & 63;
    const int h = blockIdx.y*4 + wid;
    const int w0 = blockIdx.x*64;
    const int b = blockIdx.z;

    short8 wa[9][2];
    #pragma unroll
    for (int tap = 0; tap < 9; ++tap)
        #pragma unroll
        for (int m = 0; m < 2; ++m)
            wa[tap][m] = *reinterpret_cast<const short8*>(wtp + ((tap*2 + m)*64 + lane)*8);

    f32x4 acc[2][4];
    #pragma unroll
    for (int m = 0; m < 2; ++m)
        #pragma unroll
        for (int n = 0; n < 4; ++n)
            acc[m][n] = (f32x4){0.f, 0.f, 0.f, 0.f};

    const int c0 = ((lane >> 4) & 3) * 8;
    const int pw = w0 + (lane & 15);
    const size_t ibase = (size_t)b * 512 * 512;

    #pragma unroll
    for (int dy = -1; dy <= 1; ++dy) {
        const int hh = h + dy;
        const bool hok = (unsigned)hh < 512u;
        #pragma unroll
        for (int dx = -1; dx <= 1; ++dx) {
            const int tap = (dy+1)*3 + (dx+1);
            short8 bfr[4];
            #pragma unroll
            for (int n = 0; n < 4; ++n) {
                const int ww = pw + n*16 + dx;
                short8 v = {0,0,0,0,0,0,0,0};
                if (hok && (unsigned)ww < 512u)
                    v = *reinterpret_cast<const short8*>(xt + ((ibase + (size_t)hh*512 + ww)*32 + c0));
                bfr[n] = v;
            }
            #pragma unroll
            for (int m = 0; m < 2; ++m)
                #pragma unroll
                for (int n = 0; n < 4; ++n)
                    acc[m][n] = __builtin_amdgcn_mfma_f32_16x16x32_bf16(wa[tap][m], bfr[n], acc[m][n], 0, 0, 0);
        }
    }

    if (tid < 64) sred[tid] = 0.f;
    __syncthreads();

    float bv[2][4];
    #pragma unroll
    for (int m = 0; m < 2; ++m)
        #pragma unroll
        for (int r = 0; r < 4; ++r)
            bv[m][r] = bias[m*16 + ((lane>>4)&3)*4 + r];

    float s8[8], q8[8];
    #pragma unroll
    for (int i = 0; i < 8; ++i) { s8[i] = 0.f; q8[i] = 0.f; }

    #pragma unroll
    for (int m = 0; m < 2; ++m) {
        #pragma unroll
        for (int n = 0; n < 4; ++n) {
            #pragma unroll
            for (int r = 0; r < 4; ++r) {
                const int co = m*16 + ((lane>>4)&3)*4 + r;
                const int ww = w0 + n*16 + (lane & 15);
                float val = acc[m][n][r] + bv[m][r];
                out[(((size_t)b*32 + co)*512 + h)*512 + ww] = f2bf(val);
                s8[m*4+r] += val;
                q8[m*4+r] += val*val;
            }
        }
    }
    #pragma unroll
    for (int i = 0; i < 8; ++i) {
        #pragma unroll
        for (int off = 1; off < 16; off <<= 1) {
            s8[i] += __shfl_xor(s8[i], off, 64);
            q8[i] += __shfl_xor(q8[i], off, 64);
        }
    }
    if ((lane & 15) == 0) {
        #pragma unroll
        for (int m = 0; m < 2; ++m)
            #pragma unroll
            for (int r = 0; r < 4; ++r) {
                const int co = m*16 + ((lane>>4)&3)*4 + r;
                atomicAdd(&sred[co], s8[m*4+r]);
                atomicAdd(&sred[32+co], q8[m*4+r]);
            }
    }
    __syncthreads();
    if (tid < 64) {
        int bin = (blockIdx.y*8 + blockIdx.x + blockIdx.z) & 63;
        atomicAdd(&stats[bin*64 + tid], sred[tid]);
    }
}

__global__ void k_finalize(const float* __restrict__ stats, int nbins, const float* __restrict__ g,
                           const float* __restrict__ bta, float* __restrict__ bnp)
{
    int c = threadIdx.x;
    if (c < 32) {
        float s = 0.f, q = 0.f;
        for (int i = 0; i < nbins; ++i) { s += stats[i*64 + c]; q += stats[i*64 + 32 + c]; }
        const float inv_n = 1.f/1048576.f;
        float mean = s * inv_n;
        float var  = q * inv_n - mean*mean;
        float sc = g[c] * rsqrtf(var + 1e-5f);
        bnp[c] = sc;
        bnp[32+c] = bta[c] - mean*sc;
    }
}

__global__ void k_finalize2(const float* __restrict__ ystats, const float* __restrict__ sstats,
                            const float* __restrict__ g, const float* __restrict__ bta,
                            float* __restrict__ bnp2)
{
    int c = threadIdx.x;
    if (c < 32) {
        float Sy = 0.f, Sy2 = 0.f, Sgg = 0.f, Sgu = 0.f, Sg0 = 0.f;
        for (int i = 0; i < 64; ++i){ Sy  += ystats[i*64 + c]; Sy2 += ystats[i*64 + 32 + c]; }
        for (int i = 0; i < 32; ++i){ Sgg += sstats[i*96 + c]; Sgu += sstats[i*96 + 32 + c]; Sg0 += sstats[i*96 + 64 + c]; }
        const float inv_n = 1.f/1048576.f;
        float Sfo  = Sg0 + Sy;
        float Sfo2 = Sgg*(1.f/512.f) + Sgu*(2.f/512.f) + Sy2;
        float mean = Sfo*inv_n;
        float var  = Sfo2*inv_n - mean*mean;
        float sc = g[c]*rsqrtf(var + 1e-5f);
        bnp2[c] = sc;
        bnp2[32+c] = bta[c] - mean*sc;
    }
}

// ---------------- row rfft: wave-local FFT (2 real rows per wave), bf16 in/out ----------------
__global__ __launch_bounds__(512) void k_rowfft_fwd(
    const ushort* __restrict__ cvo, const float* __restrict__ bnp,
    const float2* __restrict__ twg, uint* __restrict__ spec, float* __restrict__ ystats)
{
    __shared__ float2 tw[512];
    __shared__ float2 d[8*ROWL];
    const int tid = threadIdx.x;
    const int h0 = blockIdx.x * 16;
    const int bc = blockIdx.y;
    const int c = bc & 31;
    ld_tw<512>(tw, twg, tid);
    __syncthreads();                       // tw visible to all waves
    const float s1 = bnp[c], t1 = bnp[32+c];
    const int row = tid >> 6, l = tid & 63;
    const int o0 = ((l&7)<<3) | (l>>3);
    float2* drow = d + row*ROWL;
    const ushort* rp0 = cvo + ((size_t)bc*512 + h0 + 2*row)*512 + o0;
    const ushort* rp1 = rp0 + 512;
    float ls = 0.f, lsq = 0.f;
    float2 v[8];
    #pragma unroll
    for (int q = 0; q < 8; ++q) {
        float y0 = fmaxf(fmaf(bf2f(rp0[64*q]), s1, t1), 0.f);
        float y1 = fmaxf(fmaf(bf2f(rp1[64*q]), s1, t1), 0.f);
        ls += y0 + y1; lsq += y0*y0 + y1*y1;
        v[q] = make_float2(y0, y1);
    }
    dft8<false>(v);
    oct_write(drow, l, v);
    fft_wave12<false>(drow, tw, l);
    __syncthreads();                       // all rows done -> block-wide coalesced split
    for (int i = tid; i < 8*WF; i += 512) {
        int p = i & 7, w = i >> 3;
        float2 Z  = d[p*ROWL + LP(w)];
        float2 Zm = d[p*ROWL + LP((512 - w) & 511)];
        float x1r = 0.5f*(Z.x + Zm.x), x1i = 0.5f*(Z.y - Zm.y);
        float x2r = 0.5f*(Z.y + Zm.y), x2i = 0.5f*(Zm.x - Z.x);
        uint2 pk;
        pk.x = packbf(x1r, x1i);
        pk.y = packbf(x2r, x2i);
        *(uint2*)(spec + ((size_t)bc*WF + w)*512 + h0 + 2*p) = pk;
    }
    // per-wave y-moment reduce + atomic (no barrier needed)
    #pragma unroll
    for (int off = 32; off; off >>= 1){ ls += __shfl_down(ls, off, 64); lsq += __shfl_down(lsq, off, 64); }
    if (l == 0) {
        int bin = ((blockIdx.x << 3) + row) & 63;
        atomicAdd(&ystats[bin*64 + c], ls);
        atomicAdd(&ystats[bin*64 + 32 + c], lsq);
    }
}

// ---------------- col FFT + MLP/gate + inverse col FFT + Parseval sums (bf16 spec) ----------------
__global__ __launch_bounds__(256) void k_colfft(uint* __restrict__ spec,
    const float* __restrict__ w1, const float* __restrict__ b1,
    const float* __restrict__ w2, const float* __restrict__ b2,
    const float2* __restrict__ twg, float* __restrict__ sstats)
{
    __shared__ float2 tw[512];
    __shared__ float2 d[4*ROWL];
    __shared__ float wl[80];
    const int tid = threadIdx.x;
    const int w = blockIdx.x;
    const int k = blockIdx.y;
    const int b = blockIdx.z;
    ld_tw<256>(tw, twg, tid);
    if (tid < 16) {
        wl[tid]      = w1[k*16 + tid];
        wl[16 + tid] = w1[128 + k*16 + tid];
        wl[32 + tid] = w2[k*16 + tid];
        wl[48 + tid] = w2[128 + k*16 + tid];
    } else if (tid < 20) {
        int o = tid - 16;
        wl[64 + o] = b1[k*4 + o];
        wl[68 + o] = b1[32 + k*4 + o];
        wl[72 + o] = b2[k*4 + o];
        wl[76 + o] = b2[32 + k*4 + o];
    }
    __syncthreads();                       // tw + wl visible
    const size_t base0 = ((size_t)(b*32 + k*4)*WF + w) * 512;
    const int cc = tid >> 6, l = tid & 63;
    const int o0 = ((l&7)<<3) | (l>>3);
    float2* drow = d + cc*ROWL;
    const size_t cbase = base0 + (size_t)cc*(WF*512);
    {   // forward stage 0 straight from global (wave-local row)
        const uint* sp = spec + cbase + o0;
        float2 v[8];
        #pragma unroll
        for (int q = 0; q < 8; ++q) v[q] = unpackbf(sp[64*q]);
        dft8<false>(v);
        oct_write(drow, l, v);
    }
    fft_wave12<false>(drow, tw, l);
    __syncthreads();                       // all 4 channel rows ready for MLP
    #pragma unroll
    for (int rep = 0; rep < 2; ++rep) {
        const int ph = LP(rep*256 + tid);
        float xr[4], xi[4];
        #pragma unroll
        for (int i = 0; i < 4; ++i) {
            float2 vv = d[i*ROWL + ph];
            xr[i] = vv.x * (1.f/512.f);
            xi[i] = vv.y * (1.f/512.f);
        }
        float o1r[4], o1i[4];
        #pragma unroll
        for (int o = 0; o < 4; ++o) {
            float sr = wl[64+o], si = wl[68+o];
            #pragma unroll
            for (int i = 0; i < 4; ++i) {
                float wr = wl[i*4+o], wi = wl[16 + i*4+o];
                sr += xr[i]*wr - xi[i]*wi;
                si += xi[i]*wr + xr[i]*wi;
            }
            o1r[o] = fmaxf(sr, 0.f);
            o1i[o] = fmaxf(si, 0.f);
        }
        #pragma unroll
        for (int o = 0; o < 4; ++o) {
            float sr = wl[72+o], si = wl[76+o];
            #pragma unroll
            for (int i = 0; i < 4; ++i) {
                float wr = wl[32 + i*4+o], wi = wl[48 + i*4+o];
                sr += o1r[i]*wr - o1i[i]*wi;
                si += o1i[i]*wr + o1r[i]*wi;
            }
            sr = (sr > LAM) ? sr - LAM : ((sr < -LAM) ? sr + LAM : 0.f);
            si = (si > LAM) ? si - LAM : ((si < -LAM) ? si + LAM : 0.f);
            d[o*ROWL + ph] = make_float2(sr*xr[o] - si*xi[o], sr*xi[o] + si*xr[o]);
        }
    }
    __syncthreads();                       // MLP writes visible to owning waves
    {   // inverse stage 0 (wave-local)
        float2 v[8];
        oct_gather(drow, o0, v);
        dft8<true>(v);
        WSYNC();
        oct_write(drow, l, v);
    }
    fft_wave12<true>(drow, tw, l);
    // wave-local epilogue: write + Parseval sums for own channel
    const bool edge = (w == 0) || (w == 256);
    float fgg = 0.f, fgu = 0.f, fg0 = 0.f;
    #pragma unroll
    for (int it = 0; it < 4; ++it) {
        const int pos = it*64 + l;
        uint2 up = *(const uint2*)(spec + cbase + 2*pos);
        float2 u0 = unpackbf(up.x), u1 = unpackbf(up.y);
        float4 vv = *(const float4*)(drow + LP(2*pos));
        uint2 gp;
        gp.x = packbf(vv.x, vv.y);
        gp.y = packbf(vv.z, vv.w);
        *(uint2*)(spec + cbase + 2*pos) = gp;
        float2 g0 = unpackbf(gp.x), g1 = unpackbf(gp.y);   // rounded values (consistent with storage)
        if (edge) {
            fgg += g0.x*g0.x + g1.x*g1.x;
            fgu += g0.x*u0.x + g1.x*u1.x;
            if (w == 0) fg0 += g0.x + g1.x;
        } else {
            fgg += 2.f*(g0.x*g0.x + g0.y*g0.y + g1.x*g1.x + g1.y*g1.y);
            fgu += 2.f*(g0.x*u0.x + g0.y*u0.y + g1.x*u1.x + g1.y*u1.y);
        }
    }
    #pragma unroll
    for (int off = 32; off; off >>= 1){
        fgg += __shfl_down(fgg, off, 64);
        fgu += __shfl_down(fgu, off, 64);
        fg0 += __shfl_down(fg0, off, 64);
    }
    if (l == 0) {
        int bin = (w + b*8 + k) & 31;
        atomicAdd(&sstats[bin*96 + k*4 + cc], fgg);
        atomicAdd(&sstats[bin*96 + 32 + k*4 + cc], fgu);
        if (w == 0) atomicAdd(&sstats[bin*96 + 64 + k*4 + cc], fg0);
    }
}

// ---------------- row irfft: wave-local inverse FFT + BN2 + final ReLU ----------------
__global__ __launch_bounds__(512) void k_rowfft_inv(
    const uint* __restrict__ spec, const ushort* __restrict__ cvo,
    const float* __restrict__ bnp, const float* __restrict__ bnp2,
    const float2* __restrict__ twg, float* __restrict__ out)
{
    __shared__ float2 tw[512];
    __shared__ float2 d[8*ROWL];
    const int tid = threadIdx.x;
    const int h0 = blockIdx.x * 16;
    const int bc = blockIdx.y;
    const int c = bc & 31;
    ld_tw<512>(tw, twg, tid);
    // block-wide coalesced load + Hermitian mirror
    for (int i = tid; i < 8*WF; i += 512) {
        int p = i & 7, w = i >> 3;
        uint2 pk = *(const uint2*)(spec + ((size_t)bc*WF + w)*512 + h0 + 2*p);
        float2 X1 = unpackbf(pk.x), X2 = unpackbf(pk.y);
        if (w == 0 || w == 256) { X1.y = 0.f; X2.y = 0.f; }   // irfft drops imag at DC/Nyquist
        d[p*ROWL + LP(w)] = make_float2(X1.x - X2.y, X1.y + X2.x);
        if ((unsigned)(w - 1) < 255u)
            d[p*ROWL + LP(512 - w)] = make_float2(X1.x + X2.y, X2.x - X1.y);
    }
    __syncthreads();                       // covers tw + mirror fill
    const int row = tid >> 6, l = tid & 63;
    const int o0 = ((l&7)<<3) | (l>>3);
    float2* drow = d + row*ROWL;
    {
        float2 v[8];
        oct_gather(drow, o0, v);
        dft8<true>(v);
        WSYNC();
        oct_write(drow, l, v);
    }
    fft_wave12<true>(drow, tw, l);
    // wave-local output: wave row -> output rows h0+2row, h0+2row+1
    const float s1 = bnp[c],  t1 = bnp[32+c];
    const float s2 = bnp2[c], t2 = bnp2[32+c];
    const size_t gbase = ((size_t)bc*512 + h0 + 2*row)*512;
    #pragma unroll
    for (int q = 0; q < 8; ++q) {
        const int col = q*64 + l;
        float2 v = drow[LP(col)];
        float y0 = fmaxf(fmaf(bf2f(cvo[gbase + col]), s1, t1), 0.f);
        float fo0 = fmaf(v.x, (1.f/512.f), y0);
        out[gbase + col] = fmaxf(y0 + fmaf(fo0, s2, t2), 0.f);
        float y1 = fmaxf(fmaf(bf2f(cvo[gbase + 512 + col]), s1, t1), 0.f);
        float fo1 = fmaf(v.y, (1.f/512.f), y1);
        out[gbase + 512 + col] = fmaxf(y1 + fmaf(fo1, s2, t2), 0.f);
    }
}

extern "C" void kernel_launch(void* const* d_in, const int* in_sizes, int n_in,
                              void* d_out, int out_size, void* d_ws, size_t ws_size,
                              hipStream_t stream)
{
    const float* x      = (const float*)d_in[0];
    const float* conv_w = (const float*)d_in[1];
    const float* conv_b = (const float*)d_in[2];
    const float* bn1g   = (const float*)d_in[3];
    const float* bn1b   = (const float*)d_in[4];
    const float* w1     = (const float*)d_in[5];
    const float* b1     = (const float*)d_in[6];
    const float* w2     = (const float*)d_in[7];
    const float* b2     = (const float*)d_in[8];
    const float* bn2g   = (const float*)d_in[9];
    const float* bn2b   = (const float*)d_in[10];
    float* out = (float*)d_out;

    char* ws = (char*)d_ws;
    uint*   spec  = (uint*)ws;                              // 67,371,008 B (bf16 pairs)
    ushort* xt    = (ushort*)ws;                            // aliases spec (dead before spec written)
    ushort* cvo   = (ushort*)(ws + 67371008);               // 67,108,864 B (bf16)
    ushort* wtp   = (ushort*)(ws + 67371008 + 67108864);    // 18,432 B
    float*  stats = (float*)(ws + 67371008 + 67108864 + 18432);
    float* stats1 = stats;             // 4096 f (bn1 bins)
    float* ystats = stats + 4096;      // 4096 f
    float* sstats = stats + 8192;      // 3072 f
    float* bnp1   = stats + 11264;     // 64 f
    float* bnp2   = stats + 11328;     // 64 f
    float2* twg   = (float2*)(stats + 11392); // 512 float2

    hipMemsetAsync(stats, 0, 11264*sizeof(float), stream);
    k_twiddle<<<2, 256, 0, stream>>>(twg);
    k_wprep<<<36, 256, 0, stream>>>(conv_w, wtp);
    k_transpose<<<dim3(8,512,4), 256, 0, stream>>>(x, xt);
    k_conv_mfma<<<dim3(8,128,4), 256, 0, stream>>>(xt, wtp, conv_b, cvo, stats1);
    k_finalize<<<1, 64, 0, stream>>>(stats1, 64, bn1g, bn1b, bnp1);
    k_rowfft_fwd<<<dim3(32,128), 512, 0, stream>>>(cvo, bnp1, twg, spec, ystats);
    k_colfft<<<dim3(257,8,4), 256, 0, stream>>>(spec, w1, b1, w2, b2, twg, sstats);
    k_finalize2<<<1, 64, 0, stream>>>(ystats, sstats, bn2g, bn2b, bnp2);
    k_rowfft_inv<<<dim3(32,128), 512, 0, stream>>>(spec, cvo, bnp1, bnp2, twg, out);
}

// Round 9
// 337.596 us; speedup vs baseline: 1.4614x; 1.0370x over previous
//
#include <hip/hip_runtime.h>

#define WF 257
#define LAM 0.01f
#define ROWH 540
#define LPH(i) ((i) + (((i)>>6)<<2))

// compiler fence + wave scheduling barrier: intra-wave LDS phase handoff
#define WSYNC() do { asm volatile("" ::: "memory"); __builtin_amdgcn_wave_barrier(); asm volatile("" ::: "memory"); } while(0)

typedef __attribute__((ext_vector_type(8))) short short8;
typedef __attribute__((ext_vector_type(4))) float f32x4;
typedef __attribute__((ext_vector_type(2))) __fp16 h2v;

__device__ __forceinline__ ushort f2bf(float f){
    unsigned u = __float_as_uint(f);
    unsigned r = (u + 0x7fffu + ((u >> 16) & 1u)) >> 16;
    return (ushort)r;
}
__device__ __forceinline__ float bf2f(ushort u){ return __uint_as_float((uint)u << 16); }
__device__ __forceinline__ uint packbf(float a, float b){
    return (uint)f2bf(a) | ((uint)f2bf(b) << 16);
}
__device__ __forceinline__ float2 unpackbf(uint u){
    return make_float2(__uint_as_float(u << 16), __uint_as_float(u & 0xffff0000u));
}
// fp16x2 pack/unpack for LDS exchange
__device__ __forceinline__ uint packh(float a, float b){
    h2v h = __builtin_amdgcn_cvt_pkrtz(a, b);
    return *(uint*)&h;
}
__device__ __forceinline__ uint packh2(float2 v){ return packh(v.x, v.y); }
__device__ __forceinline__ float2 unph(uint u){
    h2v h = *(h2v*)&u;
    return make_float2((float)h[0], (float)h[1]);
}

__device__ __forceinline__ float2 cmul(float2 a, float2 b){
    return make_float2(a.x*b.x - a.y*b.y, a.x*b.y + a.y*b.x);
}
__device__ __forceinline__ float2 cadd(float2 a, float2 b){ return make_float2(a.x+b.x, a.y+b.y); }
__device__ __forceinline__ float2 csub(float2 a, float2 b){ return make_float2(a.x-b.x, a.y-b.y); }

template<int NTHREADS>
__device__ __forceinline__ void ld_tw(float2* tw, const float2* __restrict__ twg, int tid){
    for (int t = tid; t < 256; t += NTHREADS)
        ((float4*)tw)[t] = ((const float4*)twg)[t];
}

template<bool INV>
__device__ __forceinline__ float2 twz(const float2* tw, int idx){
    float2 w = tw[idx];
    if (INV) w.y = -w.y;
    return w;
}

template<bool INV>
__device__ __forceinline__ void dft8(float2 v[8]) {
    const float R = 0.70710678118654752f;
    float2 y0=v[0], y1=v[4], y2=v[2], y3=v[6], y4=v[1], y5=v[5], y6=v[3], y7=v[7];
    float2 t;
    t=y1; y1=csub(y0,t); y0=cadd(y0,t);
    t=y3; y3=csub(y2,t); y2=cadd(y2,t);
    t=y5; y5=csub(y4,t); y4=cadd(y4,t);
    t=y7; y7=csub(y6,t); y6=cadd(y6,t);
    t=y2; y2=csub(y0,t); y0=cadd(y0,t);
    t = INV ? make_float2(-y3.y, y3.x) : make_float2(y3.y, -y3.x);
    y3=csub(y1,t); y1=cadd(y1,t);
    t=y6; y6=csub(y4,t); y4=cadd(y4,t);
    t = INV ? make_float2(-y7.y, y7.x) : make_float2(y7.y, -y7.x);
    y7=csub(y5,t); y5=cadd(y5,t);
    t=y4; y4=csub(y0,t); y0=cadd(y0,t);
    { float2 w8 = INV ? make_float2(R, R) : make_float2(R,-R);
      t=cmul(y5,w8); y5=csub(y1,t); y1=cadd(y1,t); }
    t = INV ? make_float2(-y6.y, y6.x) : make_float2(y6.y, -y6.x);
    y6=csub(y2,t); y2=cadd(y2,t);
    { float2 w8 = INV ? make_float2(-R, R) : make_float2(-R,-R);
      t=cmul(y7,w8); y7=csub(y3,t); y3=cadd(y3,t); }
    v[0]=y0; v[1]=y1; v[2]=y2; v[3]=y3; v[4]=y4; v[5]=y5; v[6]=y6; v[7]=y7;
}

// write stage-0 octet l contiguously (2x b128, 16B aligned: LPH(8l) % 4 == 0)
__device__ __forceinline__ void oct_write(uint* drow, int l, const float2 v[8]){
    uint* p = drow + LPH(8*l);
    *(uint4*)p       = make_uint4(packh2(v[0]), packh2(v[1]), packh2(v[2]), packh2(v[3]));
    *(uint4*)(p + 4) = make_uint4(packh2(v[4]), packh2(v[5]), packh2(v[6]), packh2(v[7]));
}

// gather stage-0 octet from natural-order row: LPH(o0+64q) = LPH(o0) + 68q
__device__ __forceinline__ void oct_gather(const uint* drow, int o0, float2 v[8]){
    const uint* b = drow + LPH(o0);
    #pragma unroll
    for (int q = 0; q < 8; ++q) v[q] = unph(b[68*q]);
}

// stages 1+2 of a 512-pt FFT on ONE wave's private row (fp16x2 LDS). No block barriers.
template<bool INV>
__device__ __forceinline__ void fft_wave12(uint* drow, const float2* tw, int l)
{
    WSYNC();
    {
        int a = l&7, m = l>>3;
        uint* b = drow + 68*m + a;           // padded base of {64m + 8j + a}
        float2 v[8];
        v[0] = unph(b[0]);
        #pragma unroll
        for (int j = 1; j < 8; ++j)
            v[j] = cmul(unph(b[8*j]), twz<INV>(tw, 8*a*j));
        dft8<INV>(v);
        #pragma unroll
        for (int j = 0; j < 8; ++j) b[8*j] = packh2(v[j]);
    }
    WSYNC();
    {
        uint* b = drow + l;                  // padded base of {l + 64q}: stride 68
        float2 v[8];
        v[0] = unph(b[0]);
        #pragma unroll
        for (int q = 1; q < 8; ++q)
            v[q] = cmul(unph(b[68*q]), twz<INV>(tw, (l*q)&511));
        dft8<INV>(v);
        #pragma unroll
        for (int q = 0; q < 8; ++q) b[68*q] = packh2(v[q]);
    }
    WSYNC();
}

__global__ void k_twiddle(float2* __restrict__ twg){
    int t = blockIdx.x*256 + threadIdx.x;
    if (t < 512) {
        float s, c;
        sincosf((float)t * (-6.2831853071795864769f/512.0f), &s, &c);
        twg[t] = make_float2(c, s);
    }
}

__global__ void k_wprep(const float* __restrict__ w, ushort* __restrict__ wtp){
    int i = blockIdx.x*256 + threadIdx.x;
    if (i < 9216) {
        int j = i & 7, l = (i>>3) & 63, m = (i>>9) & 1, tap = i >> 10;
        int co = m*16 + (l & 15), ci = ((l>>4)&3)*8 + j;
        wtp[i] = f2bf(w[(co*32 + ci)*9 + tap]);
    }
}

// ---------------- NCHW fp32 -> NHWC bf16 transpose ----------------
__global__ __launch_bounds__(256) void k_transpose(const float* __restrict__ x, ushort* __restrict__ xt){
    __shared__ ushort tl[64][36];
    const int tid = threadIdx.x;
    const int w0 = blockIdx.x*64, h = blockIdx.y, b = blockIdx.z;
    #pragma unroll
    for (int it = 0; it < 8; ++it) {
        int i = it*256 + tid, c = i >> 6, ww = i & 63;
        tl[ww][c] = f2bf(x[(((size_t)b*32 + c)*512 + h)*512 + w0 + ww]);
    }
    __syncthreads();
    const int ww = tid >> 2, c0 = (tid & 3) * 8;
    uint4 v;
    v.x = *(const uint*)&tl[ww][c0+0];
    v.y = *(const uint*)&tl[ww][c0+2];
    v.z = *(const uint*)&tl[ww][c0+4];
    v.w = *(const uint*)&tl[ww][c0+6];
    *(uint4*)(xt + ((((size_t)b*512 + h)*512 + w0 + ww)*32 + c0)) = v;
}

// ---------------- conv 3x3 via bf16 MFMA, bf16 out, fused bias + BN1 stats ----------------
__global__ __launch_bounds__(256) void k_conv_mfma(
    const ushort* __restrict__ xt, const ushort* __restrict__ wtp,
    const float* __restrict__ bias, ushort* __restrict__ out, float* __restrict__ stats)
{
    __shared__ float sred[64];
    const int tid = threadIdx.x;
    const int wid = tid >> 6, lane = tid & 63;
    const int h = blockIdx.y*4 + wid;
    const int w0 = blockIdx.x*64;
    const int b = blockIdx.z;

    short8 wa[9][2];
    #pragma unroll
    for (int tap = 0; tap < 9; ++tap)
        #pragma unroll
        for (int m = 0; m < 2; ++m)
            wa[tap][m] = *reinterpret_cast<const short8*>(wtp + ((tap*2 + m)*64 + lane)*8);

    f32x4 acc[2][4];
    #pragma unroll
    for (int m = 0; m < 2; ++m)
        #pragma unroll
        for (int n = 0; n < 4; ++n)
            acc[m][n] = (f32x4){0.f, 0.f, 0.f, 0.f};

    const int c0 = ((lane >> 4) & 3) * 8;
    const int pw = w0 + (lane & 15);
    const size_t ibase = (size_t)b * 512 * 512;

    #pragma unroll
    for (int dy = -1; dy <= 1; ++dy) {
        const int hh = h + dy;
        const bool hok = (unsigned)hh < 512u;
        #pragma unroll
        for (int dx = -1; dx <= 1; ++dx) {
            const int tap = (dy+1)*3 + (dx+1);
            short8 bfr[4];
            #pragma unroll
            for (int n = 0; n < 4; ++n) {
                const int ww = pw + n*16 + dx;
                short8 v = {0,0,0,0,0,0,0,0};
                if (hok && (unsigned)ww < 512u)
                    v = *reinterpret_cast<const short8*>(xt + ((ibase + (size_t)hh*512 + ww)*32 + c0));
                bfr[n] = v;
            }
            #pragma unroll
            for (int m = 0; m < 2; ++m)
                #pragma unroll
                for (int n = 0; n < 4; ++n)
                    acc[m][n] = __builtin_amdgcn_mfma_f32_16x16x32_bf16(wa[tap][m], bfr[n], acc[m][n], 0, 0, 0);
        }
    }

    if (tid < 64) sred[tid] = 0.f;
    __syncthreads();

    float bv[2][4];
    #pragma unroll
    for (int m = 0; m < 2; ++m)
        #pragma unroll
        for (int r = 0; r < 4; ++r)
            bv[m][r] = bias[m*16 + ((lane>>4)&3)*4 + r];

    float s8[8], q8[8];
    #pragma unroll
    for (int i = 0; i < 8; ++i) { s8[i] = 0.f; q8[i] = 0.f; }

    #pragma unroll
    for (int m = 0; m < 2; ++m) {
        #pragma unroll
        for (int n = 0; n < 4; ++n) {
            #pragma unroll
            for (int r = 0; r < 4; ++r) {
                const int co = m*16 + ((lane>>4)&3)*4 + r;
                const int ww = w0 + n*16 + (lane & 15);
                float val = acc[m][n][r] + bv[m][r];
                out[(((size_t)b*32 + co)*512 + h)*512 + ww] = f2bf(val);
                s8[m*4+r] += val;
                q8[m*4+r] += val*val;
            }
        }
    }
    #pragma unroll
    for (int i = 0; i < 8; ++i) {
        #pragma unroll
        for (int off = 1; off < 16; off <<= 1) {
            s8[i] += __shfl_xor(s8[i], off, 64);
            q8[i] += __shfl_xor(q8[i], off, 64);
        }
    }
    if ((lane & 15) == 0) {
        #pragma unroll
        for (int m = 0; m < 2; ++m)
            #pragma unroll
            for (int r = 0; r < 4; ++r) {
                const int co = m*16 + ((lane>>4)&3)*4 + r;
                atomicAdd(&sred[co], s8[m*4+r]);
                atomicAdd(&sred[32+co], q8[m*4+r]);
            }
    }
    __syncthreads();
    if (tid < 64) {
        int bin = (blockIdx.y*8 + blockIdx.x + blockIdx.z) & 63;
        atomicAdd(&stats[bin*64 + tid], sred[tid]);
    }
}

__global__ void k_finalize(const float* __restrict__ stats, int nbins, const float* __restrict__ g,
                           const float* __restrict__ bta, float* __restrict__ bnp)
{
    int c = threadIdx.x;
    if (c < 32) {
        float s = 0.f, q = 0.f;
        for (int i = 0; i < nbins; ++i) { s += stats[i*64 + c]; q += stats[i*64 + 32 + c]; }
        const float inv_n = 1.f/1048576.f;
        float mean = s * inv_n;
        float var  = q * inv_n - mean*mean;
        float sc = g[c] * rsqrtf(var + 1e-5f);
        bnp[c] = sc;
        bnp[32+c] = bta[c] - mean*sc;
    }
}

__global__ void k_finalize2(const float* __restrict__ ystats, const float* __restrict__ sstats,
                            const float* __restrict__ g, const float* __restrict__ bta,
                            float* __restrict__ bnp2)
{
    int c = threadIdx.x;
    if (c < 32) {
        float Sy = 0.f, Sy2 = 0.f, Sgg = 0.f, Sgu = 0.f, Sg0 = 0.f;
        for (int i = 0; i < 64; ++i){ Sy  += ystats[i*64 + c]; Sy2 += ystats[i*64 + 32 + c]; }
        for (int i = 0; i < 32; ++i){ Sgg += sstats[i*96 + c]; Sgu += sstats[i*96 + 32 + c]; Sg0 += sstats[i*96 + 64 + c]; }
        const float inv_n = 1.f/1048576.f;
        float Sfo  = Sg0 + Sy;
        float Sfo2 = Sgg*(1.f/512.f) + Sgu*(2.f/512.f) + Sy2;
        float mean = Sfo*inv_n;
        float var  = Sfo2*inv_n - mean*mean;
        float sc = g[c]*rsqrtf(var + 1e-5f);
        bnp2[c] = sc;
        bnp2[32+c] = bta[c] - mean*sc;
    }
}

// ---------------- row rfft: wave-local FFT (2 real rows per wave), bf16 in/out ----------------
__global__ __launch_bounds__(512) void k_rowfft_fwd(
    const ushort* __restrict__ cvo, const float* __restrict__ bnp,
    const float2* __restrict__ twg, uint* __restrict__ spec, float* __restrict__ ystats)
{
    __shared__ float2 tw[512];
    __shared__ uint d[8*ROWH];
    const int tid = threadIdx.x;
    const int h0 = blockIdx.x * 16;
    const int bc = blockIdx.y;
    const int c = bc & 31;
    ld_tw<512>(tw, twg, tid);
    __syncthreads();                       // tw visible to all waves
    const float s1 = bnp[c], t1 = bnp[32+c];
    const int row = tid >> 6, l = tid & 63;
    const int o0 = ((l&7)<<3) | (l>>3);
    uint* drow = d + row*ROWH;
    const ushort* rp0 = cvo + ((size_t)bc*512 + h0 + 2*row)*512 + o0;
    const ushort* rp1 = rp0 + 512;
    float ls = 0.f, lsq = 0.f;
    float2 v[8];
    #pragma unroll
    for (int q = 0; q < 8; ++q) {
        float y0 = fmaxf(fmaf(bf2f(rp0[64*q]), s1, t1), 0.f);
        float y1 = fmaxf(fmaf(bf2f(rp1[64*q]), s1, t1), 0.f);
        ls += y0 + y1; lsq += y0*y0 + y1*y1;
        v[q] = make_float2(y0, y1);
    }
    dft8<false>(v);
    oct_write(drow, l, v);
    fft_wave12<false>(drow, tw, l);
    __syncthreads();                       // all rows done -> block-wide coalesced split
    for (int i = tid; i < 8*WF; i += 512) {
        int p = i & 7, w = i >> 3;
        float2 Z  = unph(d[p*ROWH + LPH(w)]);
        float2 Zm = unph(d[p*ROWH + LPH((512 - w) & 511)]);
        float x1r = 0.5f*(Z.x + Zm.x), x1i = 0.5f*(Z.y - Zm.y);
        float x2r = 0.5f*(Z.y + Zm.y), x2i = 0.5f*(Zm.x - Z.x);
        uint2 pk;
        pk.x = packbf(x1r, x1i);
        pk.y = packbf(x2r, x2i);
        *(uint2*)(spec + ((size_t)bc*WF + w)*512 + h0 + 2*p) = pk;
    }
    #pragma unroll
    for (int off = 32; off; off >>= 1){ ls += __shfl_down(ls, off, 64); lsq += __shfl_down(lsq, off, 64); }
    if (l == 0) {
        int bin = ((blockIdx.x << 3) + row) & 63;
        atomicAdd(&ystats[bin*64 + c], ls);
        atomicAdd(&ystats[bin*64 + 32 + c], lsq);
    }
}

// ---------------- col FFT + MLP/gate + inverse col FFT + Parseval sums (bf16 spec) ----------------
__global__ __launch_bounds__(256) void k_colfft(uint* __restrict__ spec,
    const float* __restrict__ w1, const float* __restrict__ b1,
    const float* __restrict__ w2, const float* __restrict__ b2,
    const float2* __restrict__ twg, float* __restrict__ sstats)
{
    __shared__ float2 tw[512];
    __shared__ uint d[4*ROWH];
    __shared__ float wl[80];
    const int tid = threadIdx.x;
    const int w = blockIdx.x;
    const int k = blockIdx.y;
    const int b = blockIdx.z;
    ld_tw<256>(tw, twg, tid);
    if (tid < 16) {
        wl[tid]      = w1[k*16 + tid];
        wl[16 + tid] = w1[128 + k*16 + tid];
        wl[32 + tid] = w2[k*16 + tid];
        wl[48 + tid] = w2[128 + k*16 + tid];
    } else if (tid < 20) {
        int o = tid - 16;
        wl[64 + o] = b1[k*4 + o];
        wl[68 + o] = b1[32 + k*4 + o];
        wl[72 + o] = b2[k*4 + o];
        wl[76 + o] = b2[32 + k*4 + o];
    }
    __syncthreads();                       // tw + wl visible
    const size_t base0 = ((size_t)(b*32 + k*4)*WF + w) * 512;
    const int cc = tid >> 6, l = tid & 63;
    const int o0 = ((l&7)<<3) | (l>>3);
    uint* drow = d + cc*ROWH;
    const size_t cbase = base0 + (size_t)cc*(WF*512);
    {   // forward stage 0 straight from global, ortho 1/512 folded in (fp16 range + exact MLP input)
        const uint* sp = spec + cbase + o0;
        float2 v[8];
        #pragma unroll
        for (int q = 0; q < 8; ++q) {
            float2 u = unpackbf(sp[64*q]);
            v[q] = make_float2(u.x*(1.f/512.f), u.y*(1.f/512.f));
        }
        dft8<false>(v);
        oct_write(drow, l, v);
    }
    fft_wave12<false>(drow, tw, l);
    __syncthreads();                       // all 4 channel rows ready for MLP
    #pragma unroll
    for (int rep = 0; rep < 2; ++rep) {
        const int ph = LPH(rep*256 + tid);
        float xr[4], xi[4];
        #pragma unroll
        for (int i = 0; i < 4; ++i) {
            float2 vv = unph(d[i*ROWH + ph]);
            xr[i] = vv.x;
            xi[i] = vv.y;
        }
        float o1r[4], o1i[4];
        #pragma unroll
        for (int o = 0; o < 4; ++o) {
            float sr = wl[64+o], si = wl[68+o];
            #pragma unroll
            for (int i = 0; i < 4; ++i) {
                float wr = wl[i*4+o], wi = wl[16 + i*4+o];
                sr += xr[i]*wr - xi[i]*wi;
                si += xi[i]*wr + xr[i]*wi;
            }
            o1r[o] = fmaxf(sr, 0.f);
            o1i[o] = fmaxf(si, 0.f);
        }
        #pragma unroll
        for (int o = 0; o < 4; ++o) {
            float sr = wl[72+o], si = wl[76+o];
            #pragma unroll
            for (int i = 0; i < 4; ++i) {
                float wr = wl[32 + i*4+o], wi = wl[48 + i*4+o];
                sr += o1r[i]*wr - o1i[i]*wi;
                si += o1i[i]*wr + o1r[i]*wi;
            }
            sr = (sr > LAM) ? sr - LAM : ((sr < -LAM) ? sr + LAM : 0.f);
            si = (si > LAM) ? si - LAM : ((si < -LAM) ? si + LAM : 0.f);
            d[o*ROWH + ph] = packh(sr*xr[o] - si*xi[o], sr*xi[o] + si*xr[o]);
        }
    }
    __syncthreads();                       // MLP writes visible to owning waves
    {   // inverse stage 0 (wave-local)
        float2 v[8];
        oct_gather(drow, o0, v);
        dft8<true>(v);
        WSYNC();
        oct_write(drow, l, v);
    }
    fft_wave12<true>(drow, tw, l);
    // wave-local epilogue: write + Parseval sums for own channel
    const bool edge = (w == 0) || (w == 256);
    float fgg = 0.f, fgu = 0.f, fg0 = 0.f;
    #pragma unroll
    for (int it = 0; it < 4; ++it) {
        const int pos = it*64 + l;
        uint2 up = *(const uint2*)(spec + cbase + 2*pos);
        float2 u0 = unpackbf(up.x), u1 = unpackbf(up.y);
        uint2 dv = *(const uint2*)(drow + LPH(2*pos));
        float2 z0 = unph(dv.x), z1 = unph(dv.y);
        uint2 gp;
        gp.x = packbf(z0.x, z0.y);
        gp.y = packbf(z1.x, z1.y);
        *(uint2*)(spec + cbase + 2*pos) = gp;
        float2 g0 = unpackbf(gp.x), g1 = unpackbf(gp.y);   // rounded values (consistent with storage)
        if (edge) {
            fgg += g0.x*g0.x + g1.x*g1.x;
            fgu += g0.x*u0.x + g1.x*u1.x;
            if (w == 0) fg0 += g0.x + g1.x;
        } else {
            fgg += 2.f*(g0.x*g0.x + g0.y*g0.y + g1.x*g1.x + g1.y*g1.y);
            fgu += 2.f*(g0.x*u0.x + g0.y*u0.y + g1.x*u1.x + g1.y*u1.y);
        }
    }
    #pragma unroll
    for (int off = 32; off; off >>= 1){
        fgg += __shfl_down(fgg, off, 64);
        fgu += __shfl_down(fgu, off, 64);
        fg0 += __shfl_down(fg0, off, 64);
    }
    if (l == 0) {
        int bin = (w + b*8 + k) & 31;
        atomicAdd(&sstats[bin*96 + k*4 + cc], fgg);
        atomicAdd(&sstats[bin*96 + 32 + k*4 + cc], fgu);
        if (w == 0) atomicAdd(&sstats[bin*96 + 64 + k*4 + cc], fg0);
    }
}

// ---------------- row irfft: wave-local inverse FFT + BN2 + final ReLU ----------------
__global__ __launch_bounds__(512) void k_rowfft_inv(
    const uint* __restrict__ spec, const ushort* __restrict__ cvo,
    const float* __restrict__ bnp, const float* __restrict__ bnp2,
    const float2* __restrict__ twg, float* __restrict__ out)
{
    __shared__ float2 tw[512];
    __shared__ uint d[8*ROWH];
    const int tid = threadIdx.x;
    const int h0 = blockIdx.x * 16;
    const int bc = blockIdx.y;
    const int c = bc & 31;
    ld_tw<512>(tw, twg, tid);
    // block-wide coalesced load + Hermitian mirror; 1/512 folded in (fp16 range)
    for (int i = tid; i < 8*WF; i += 512) {
        int p = i & 7, w = i >> 3;
        uint2 pk = *(const uint2*)(spec + ((size_t)bc*WF + w)*512 + h0 + 2*p);
        float2 X1 = unpackbf(pk.x), X2 = unpackbf(pk.y);
        if (w == 0 || w == 256) { X1.y = 0.f; X2.y = 0.f; }   // irfft drops imag at DC/Nyquist
        const float s = 1.f/512.f;
        d[p*ROWH + LPH(w)] = packh((X1.x - X2.y)*s, (X1.y + X2.x)*s);
        if ((unsigned)(w - 1) < 255u)
            d[p*ROWH + LPH(512 - w)] = packh((X1.x + X2.y)*s, (X2.x - X1.y)*s);
    }
    __syncthreads();                       // covers tw + mirror fill
    const int row = tid >> 6, l = tid & 63;
    const int o0 = ((l&7)<<3) | (l>>3);
    uint* drow = d + row*ROWH;
    {
        float2 v[8];
        oct_gather(drow, o0, v);
        dft8<true>(v);
        WSYNC();
        oct_write(drow, l, v);
    }
    fft_wave12<true>(drow, tw, l);
    // wave-local output: wave row -> output rows h0+2row, h0+2row+1
    const float s1 = bnp[c],  t1 = bnp[32+c];
    const float s2 = bnp2[c], t2 = bnp2[32+c];
    const size_t gbase = ((size_t)bc*512 + h0 + 2*row)*512;
    #pragma unroll
    for (int q = 0; q < 8; ++q) {
        const int col = q*64 + l;
        float2 v = unph(drow[LPH(col)]);
        float y0 = fmaxf(fmaf(bf2f(cvo[gbase + col]), s1, t1), 0.f);
        float fo0 = v.x + y0;
        out[gbase + col] = fmaxf(y0 + fmaf(fo0, s2, t2), 0.f);
        float y1 = fmaxf(fmaf(bf2f(cvo[gbase + 512 + col]), s1, t1), 0.f);
        float fo1 = v.y + y1;
        out[gbase + 512 + col] = fmaxf(y1 + fmaf(fo1, s2, t2), 0.f);
    }
}

extern "C" void kernel_launch(void* const* d_in, const int* in_sizes, int n_in,
                              void* d_out, int out_size, void* d_ws, size_t ws_size,
                              hipStream_t stream)
{
    const float* x      = (const float*)d_in[0];
    const float* conv_w = (const float*)d_in[1];
    const float* conv_b = (const float*)d_in[2];
    const float* bn1g   = (const float*)d_in[3];
    const float* bn1b   = (const float*)d_in[4];
    const float* w1     = (const float*)d_in[5];
    const float* b1     = (const float*)d_in[6];
    const float* w2     = (const float*)d_in[7];
    const float* b2     = (const float*)d_in[8];
    const float* bn2g   = (const float*)d_in[9];
    const float* bn2b   = (const float*)d_in[10];
    float* out = (float*)d_out;

    char* ws = (char*)d_ws;
    uint*   spec  = (uint*)ws;                              // 67,371,008 B (bf16 pairs)
    ushort* xt    = (ushort*)ws;                            // aliases spec (dead before spec written)
    ushort* cvo   = (ushort*)(ws + 67371008);               // 67,108,864 B (bf16)
    ushort* wtp   = (ushort*)(ws + 67371008 + 67108864);    // 18,432 B
    float*  stats = (float*)(ws + 67371008 + 67108864 + 18432);
    float* stats1 = stats;             // 4096 f (bn1 bins)
    float* ystats = stats + 4096;      // 4096 f
    float* sstats = stats + 8192;      // 3072 f
    float* bnp1   = stats + 11264;     // 64 f
    float* bnp2   = stats + 11328;     // 64 f
    float2* twg   = (float2*)(stats + 11392); // 512 float2

    (void)hipMemsetAsync(stats, 0, 11264*sizeof(float), stream);
    k_twiddle<<<2, 256, 0, stream>>>(twg);
    k_wprep<<<36, 256, 0, stream>>>(conv_w, wtp);
    k_transpose<<<dim3(8,512,4), 256, 0, stream>>>(x, xt);
    k_conv_mfma<<<dim3(8,128,4), 256, 0, stream>>>(xt, wtp, conv_b, cvo, stats1);
    k_finalize<<<1, 64, 0, stream>>>(stats1, 64, bn1g, bn1b, bnp1);
    k_rowfft_fwd<<<dim3(32,128), 512, 0, stream>>>(cvo, bnp1, twg, spec, ystats);
    k_colfft<<<dim3(257,8,4), 256, 0, stream>>>(spec, w1, b1, w2, b2, twg, sstats);
    k_finalize2<<<1, 64, 0, stream>>>(ystats, sstats, bn2g, bn2b, bnp2);
    k_rowfft_inv<<<dim3(32,128), 512, 0, stream>>>(spec, cvo, bnp1, bnp2, twg, out);
}